// Round 5
// baseline (695.380 us; speedup 1.0000x reference)
//
#include <hip/hip_runtime.h>

// GraphSAGE 2-layer forward on MI355X.
// Round 5: CSR build via two-level bucket sort (kills csr_fill's 16x write
// amplification: 107 MB scattered stores -> ~14 MB windowed stores).
//   bin_count   : LDS histogram of dst>>7 (782 bins of 128 nodes)
//   bin_scan    : single-block scan -> bin_base / bin_cursor
//   bin_scatter : edge -> packed (dst_local<<20 | src) at atomic bin slot
//   bin_fill    : per-bin workgroup: LDS per-node count+scan -> row_start,
//                 then write csr_src into the bin's contiguous window
// Rest unchanged: bf16 cast, transposed bf16 weights, MFMA 16x16x32 GEMMs,
// latency-optimized 2-edge/iter gathers, transform-then-aggregate layer 2.

typedef __attribute__((ext_vector_type(8))) short bf16x8;
typedef __attribute__((ext_vector_type(4))) float f32x4;

#define BIN_SHIFT 7
#define BIN_SIZE  128

#define OFF_ROWSTART (1ull << 20)                      // 400 KB (N+1 ints)
#define OFF_BINCNT   (2ull << 20)                      // ~3 KB
#define OFF_BINBASE  ((2ull << 20) + (64ull << 10))    // ~3 KB (+ sentinel)
#define OFF_BINCUR   ((2ull << 20) + (128ull << 10))   // ~3 KB
#define OFF_PACKED   (3ull << 20)                      // 6.4 MB
#define OFF_CSR      (10ull << 20)                     // 6.4 MB
#define OFF_W1T      (17ull << 20)                     // 64 KB
#define OFF_W2T      (18ull << 20)                     // 20 KB
#define OFF_XB       (19ull << 20)                     // 25.6 MB
#define OFF_AGGB     (45ull << 20)                     // 25.6 MB
#define OFF_H1B      (71ull << 20)                     // 25.6 MB
#define OFF_T2       (97ull << 20)                     // 8 MB (bf16)

static __device__ __forceinline__ unsigned short f2b(float f) {
    unsigned int u = __float_as_uint(f);
    u += 0x7fffu + ((u >> 16) & 1u);   // round-to-nearest-even
    return (unsigned short)(u >> 16);
}
static __device__ __forceinline__ float blo(unsigned int v) { return __uint_as_float(v << 16); }
static __device__ __forceinline__ float bhi(unsigned int v) { return __uint_as_float(v & 0xffff0000u); }

// ------------------------------------------------------- CSR via bucket sort

// Pass A: per-bin edge counts. 256 grid-stride blocks, LDS histogram.
__global__ void bin_count(const int* __restrict__ dst, int* __restrict__ bin_cnt,
                          int E, int nbins) {
    __shared__ int h[1024];
    for (int i = threadIdx.x; i < nbins; i += 256) h[i] = 0;
    __syncthreads();
    for (int e = blockIdx.x * 256 + threadIdx.x; e < E; e += gridDim.x * 256)
        atomicAdd(&h[dst[e] >> BIN_SHIFT], 1);
    __syncthreads();
    for (int i = threadIdx.x; i < nbins; i += 256) {
        int v = h[i];
        if (v) atomicAdd(&bin_cnt[i], v);
    }
}

// Pass B: single-block scan of bin counts (nbins <= 1024).
__global__ void bin_scan(const int* __restrict__ bin_cnt, int* __restrict__ bin_base,
                         int* __restrict__ bin_cursor, int nbins) {
    __shared__ int s[1024];
    int t = threadIdx.x;
    int v = (t < nbins) ? bin_cnt[t] : 0;
    s[t] = v;
    __syncthreads();
    for (int off = 1; off < 1024; off <<= 1) {
        int u = (t >= off) ? s[t - off] : 0;
        __syncthreads();
        s[t] += u;
        __syncthreads();
    }
    if (t < nbins) {
        int ex = s[t] - v;
        bin_base[t] = ex;
        bin_cursor[t] = ex;
    }
    if (t == 1023) bin_base[nbins] = s[t];
}

// Pass C: scatter packed records into bin windows. pos claimed in time order
// -> concurrent writers hit neighboring addresses -> L2 write-combines.
__global__ void bin_scatter(const int* __restrict__ src, const int* __restrict__ dst,
                            int* __restrict__ bin_cursor, unsigned int* __restrict__ packed,
                            int E) {
    int e = blockIdx.x * 256 + threadIdx.x;
    if (e < E) {
        int d = dst[e];
        int b = d >> BIN_SHIFT;
        int pos = atomicAdd(&bin_cursor[b], 1);
        packed[pos] = ((unsigned int)(d & (BIN_SIZE - 1)) << 20) | (unsigned int)src[e];
    }
}

// Pass D: one workgroup per bin. Local histogram+scan gives row_start
// (row_start[node] = bin_base + local exclusive prefix); second pass writes
// csr_src into the bin's contiguous window.
__global__ __launch_bounds__(256) void bin_fill(
    const unsigned int* __restrict__ packed, const int* __restrict__ bin_base,
    int* __restrict__ row_start, int* __restrict__ csr_src, int N, int nbins, int E) {
    __shared__ int cnt[BIN_SIZE];
    __shared__ int pre[BIN_SIZE];
    __shared__ int ex[BIN_SIZE];
    int b = blockIdx.x;
    int t = threadIdx.x;
    int node0 = b << BIN_SHIFT;
    int beg = bin_base[b], end = bin_base[b + 1];

    if (t < BIN_SIZE) cnt[t] = 0;
    __syncthreads();
    for (int i = beg + t; i < end; i += 256)
        atomicAdd(&cnt[packed[i] >> 20], 1);
    __syncthreads();
    if (t < BIN_SIZE) pre[t] = cnt[t];
    __syncthreads();
    for (int off = 1; off < BIN_SIZE; off <<= 1) {
        int u = (t < BIN_SIZE && t >= off) ? pre[t - off] : 0;
        __syncthreads();
        if (t < BIN_SIZE) pre[t] += u;
        __syncthreads();
    }
    if (t < BIN_SIZE) {
        ex[t] = pre[t] - cnt[t];        // exclusive prefix
        int node = node0 + t;
        if (node < N) row_start[node] = beg + ex[t];
        cnt[t] = 0;                      // reuse as per-node cursor
    }
    if (b == nbins - 1 && t == 0) row_start[N] = E;
    __syncthreads();
    for (int i = beg + t; i < end; i += 256) {
        unsigned int p = packed[i];
        int dl = p >> 20;
        int s = p & 0xFFFFF;
        int ofs = atomicAdd(&cnt[dl], 1);
        csr_src[beg + ex[dl] + ofs] = s;
    }
}

// ------------------------------------------------------------- prep kernels

__global__ void cast_bf16(const float* __restrict__ x, unsigned short* __restrict__ xb, int n8) {
    int i = blockIdx.x * blockDim.x + threadIdx.x;
    if (i >= n8) return;
    const float4* p = (const float4*)x + (size_t)i * 2;
    float4 v0 = p[0], v1 = p[1];
    unsigned short o[8];
    o[0] = f2b(v0.x); o[1] = f2b(v0.y); o[2] = f2b(v0.z); o[3] = f2b(v0.w);
    o[4] = f2b(v1.x); o[5] = f2b(v1.y); o[6] = f2b(v1.z); o[7] = f2b(v1.w);
    *(float4*)(xb + (size_t)i * 8) = *(float4*)o;
}

__global__ void prep_w1t(const float* __restrict__ W1s, const float* __restrict__ W1n,
                         unsigned short* __restrict__ W1t) {
    int c = blockIdx.x, k = threadIdx.x;
    float v = (k < 128) ? W1s[(size_t)k * 128 + c] : W1n[(size_t)(k - 128) * 128 + c];
    W1t[(size_t)c * 256 + k] = f2b(v);
}

__global__ void prep_w2t(const float* __restrict__ W2s, const float* __restrict__ W2n,
                         unsigned short* __restrict__ W2t) {
    int c = blockIdx.x, k = threadIdx.x;
    float v = (c < 40) ? W2s[(size_t)k * 40 + c] : W2n[(size_t)k * 40 + (c - 40)];
    W2t[(size_t)c * 128 + k] = f2b(v);
}

// ------------------------------------------------------- aggregation kernels

// One wave per node, two edges/iter (half-wave per edge, uint2/lane), unroll x2.
__global__ void agg_mean_bf16(const unsigned short* __restrict__ xb,
                              const int* __restrict__ row_start,
                              const int* __restrict__ csr_src,
                              unsigned short* __restrict__ aggb, int N) {
    int wave = (blockIdx.x * blockDim.x + threadIdx.x) >> 6;
    int lane = threadIdx.x & 63;
    if (wave >= N) return;
    int half = lane >> 5;
    int l = lane & 31;
    int beg = row_start[wave], end = row_start[wave + 1];
    const uint2* x4 = (const uint2*)xb;

    float a0 = 0.f, a1 = 0.f, a2 = 0.f, a3 = 0.f;
    int e = beg + half;
    for (; e + 2 < end; e += 4) {
        int s0 = csr_src[e];
        int s1 = csr_src[e + 2];
        uint2 v0 = x4[(size_t)s0 * 32 + l];
        uint2 v1 = x4[(size_t)s1 * 32 + l];
        a0 += blo(v0.x) + blo(v1.x);
        a1 += bhi(v0.x) + bhi(v1.x);
        a2 += blo(v0.y) + blo(v1.y);
        a3 += bhi(v0.y) + bhi(v1.y);
    }
    for (; e < end; e += 2) {
        int s = csr_src[e];
        uint2 v = x4[(size_t)s * 32 + l];
        a0 += blo(v.x); a1 += bhi(v.x); a2 += blo(v.y); a3 += bhi(v.y);
    }
    a0 += __shfl_xor(a0, 32);
    a1 += __shfl_xor(a1, 32);
    a2 += __shfl_xor(a2, 32);
    a3 += __shfl_xor(a3, 32);
    if (half == 0) {
        float inv = 1.0f / fmaxf((float)(end - beg), 1.0f);
        uint2 o;
        o.x = (unsigned int)f2b(a0 * inv) | ((unsigned int)f2b(a1 * inv) << 16);
        o.y = (unsigned int)f2b(a2 * inv) | ((unsigned int)f2b(a3 * inv) << 16);
        ((uint2*)aggb)[(size_t)wave * 32 + l] = o;
    }
}

// One wave per node over bf16 t2 (40 dims = 20 uints/row).
__global__ void agg2_add(const unsigned short* __restrict__ t2b,
                         const int* __restrict__ row_start,
                         const int* __restrict__ csr_src, const float* __restrict__ b2,
                         float* __restrict__ out, int N) {
    int wave = (blockIdx.x * blockDim.x + threadIdx.x) >> 6;
    int lane = threadIdx.x & 63;
    if (wave >= N) return;
    int half = lane >> 5;
    int l = lane & 31;
    int beg = row_start[wave], end = row_start[wave + 1];
    const unsigned int* t2u = (const unsigned int*)t2b;

    float a0 = 0.f, a1 = 0.f;
    if (l < 20) {
        int e = beg + half;
        for (; e + 2 < end; e += 4) {
            int s0 = csr_src[e];
            int s1 = csr_src[e + 2];
            unsigned int v0 = t2u[(size_t)s0 * 20 + l];
            unsigned int v1 = t2u[(size_t)s1 * 20 + l];
            a0 += blo(v0) + blo(v1);
            a1 += bhi(v0) + bhi(v1);
        }
        for (; e < end; e += 2) {
            unsigned int v = t2u[(size_t)csr_src[e] * 20 + l];
            a0 += blo(v); a1 += bhi(v);
        }
    }
    a0 += __shfl_xor(a0, 32);
    a1 += __shfl_xor(a1, 32);
    if (half == 0 && l < 20) {
        float inv = 1.0f / fmaxf((float)(end - beg), 1.0f);
        float2 bb = ((const float2*)b2)[l];
        float2* op = (float2*)(out + (size_t)wave * 40 + 2 * l);
        float2 cur = *op;
        cur.x += a0 * inv + bb.x;
        cur.y += a1 * inv + bb.y;
        *op = cur;
    }
}

// ------------------------------------------------------------------- GEMM 1

__global__ __launch_bounds__(256) void gemm1_mfma(
    const unsigned short* __restrict__ xb, const unsigned short* __restrict__ aggb,
    const unsigned short* __restrict__ W1t, const float* __restrict__ b1,
    unsigned short* __restrict__ h1, int N) {

    __shared__ unsigned short As[128 * 40];
    __shared__ unsigned short Bs[128 * 40];

    int tid = threadIdx.x;
    int wave = tid >> 6, lane = tid & 63;
    int row0 = blockIdx.x * 128;
    int m = lane & 15, quad = lane >> 4;

    f32x4 acc[2][8];
#pragma unroll
    for (int i = 0; i < 2; i++)
#pragma unroll
        for (int j = 0; j < 8; j++) acc[i][j] = (f32x4){0.f, 0.f, 0.f, 0.f};

    for (int k0 = 0; k0 < 256; k0 += 32) {
        __syncthreads();
        {
            int r = tid >> 1, kk = (tid & 1) * 16;
            int row = row0 + r;
            float4 v0 = make_float4(0, 0, 0, 0), v1 = v0;
            if (row < N) {
                const unsigned short* s = (k0 < 128)
                    ? (xb + (size_t)row * 128 + k0 + kk)
                    : (aggb + (size_t)row * 128 + (k0 - 128) + kk);
                const float4* p = (const float4*)s;
                v0 = p[0]; v1 = p[1];
            }
            *(float4*)&As[r * 40 + kk] = v0;
            *(float4*)&As[r * 40 + kk + 8] = v1;
            const float4* q = (const float4*)(W1t + (size_t)r * 256 + k0 + kk);
            float4 w0 = q[0], w1 = q[1];
            *(float4*)&Bs[r * 40 + kk] = w0;
            *(float4*)&Bs[r * 40 + kk + 8] = w1;
        }
        __syncthreads();

        bf16x8 af0 = *(bf16x8*)&As[(wave * 32 + m) * 40 + quad * 8];
        bf16x8 af1 = *(bf16x8*)&As[(wave * 32 + 16 + m) * 40 + quad * 8];
#pragma unroll
        for (int j = 0; j < 8; j++) {
            bf16x8 bfg = *(bf16x8*)&Bs[(j * 16 + m) * 40 + quad * 8];
            acc[0][j] = __builtin_amdgcn_mfma_f32_16x16x32_bf16(af0, bfg, acc[0][j], 0, 0, 0);
            acc[1][j] = __builtin_amdgcn_mfma_f32_16x16x32_bf16(af1, bfg, acc[1][j], 0, 0, 0);
        }
    }

#pragma unroll
    for (int j = 0; j < 8; j++) {
        int col = j * 16 + m;
        float bias = b1[col];
#pragma unroll
        for (int i = 0; i < 2; i++) {
#pragma unroll
            for (int r = 0; r < 4; r++) {
                int row = row0 + wave * 32 + i * 16 + quad * 4 + r;
                if (row < N) {
                    float v = fmaxf(acc[i][j][r] + bias, 0.f);
                    h1[(size_t)row * 128 + col] = f2b(v);
                }
            }
        }
    }
}

// ------------------------------------------------------------------- GEMM 2

__global__ __launch_bounds__(256) void gemm2_mfma(
    const unsigned short* __restrict__ h1, const unsigned short* __restrict__ W2t,
    float* __restrict__ out, unsigned short* __restrict__ t2b, int N) {

    __shared__ unsigned short As[128 * 40];
    __shared__ unsigned short Bs[80 * 40];

    int tid = threadIdx.x;
    int wave = tid >> 6, lane = tid & 63;
    int row0 = blockIdx.x * 128;
    int m = lane & 15, quad = lane >> 4;

    f32x4 acc[2][5];
#pragma unroll
    for (int i = 0; i < 2; i++)
#pragma unroll
        for (int j = 0; j < 5; j++) acc[i][j] = (f32x4){0.f, 0.f, 0.f, 0.f};

    for (int k0 = 0; k0 < 128; k0 += 32) {
        __syncthreads();
        {
            int r = tid >> 1, kk = (tid & 1) * 16;
            int row = row0 + r;
            float4 v0 = make_float4(0, 0, 0, 0), v1 = v0;
            if (row < N) {
                const float4* p = (const float4*)(h1 + (size_t)row * 128 + k0 + kk);
                v0 = p[0]; v1 = p[1];
            }
            *(float4*)&As[r * 40 + kk] = v0;
            *(float4*)&As[r * 40 + kk + 8] = v1;
            if (tid < 160) {
                const float4* q = (const float4*)(W2t + (size_t)r * 128 + k0 + kk);
                float4 w0 = q[0], w1 = q[1];
                *(float4*)&Bs[r * 40 + kk] = w0;
                *(float4*)&Bs[r * 40 + kk + 8] = w1;
            }
        }
        __syncthreads();

        bf16x8 af0 = *(bf16x8*)&As[(wave * 32 + m) * 40 + quad * 8];
        bf16x8 af1 = *(bf16x8*)&As[(wave * 32 + 16 + m) * 40 + quad * 8];
#pragma unroll
        for (int j = 0; j < 5; j++) {
            bf16x8 bfg = *(bf16x8*)&Bs[(j * 16 + m) * 40 + quad * 8];
            acc[0][j] = __builtin_amdgcn_mfma_f32_16x16x32_bf16(af0, bfg, acc[0][j], 0, 0, 0);
            acc[1][j] = __builtin_amdgcn_mfma_f32_16x16x32_bf16(af1, bfg, acc[1][j], 0, 0, 0);
        }
    }

#pragma unroll
    for (int j = 0; j < 5; j++) {
        int col = j * 16 + m;
#pragma unroll
        for (int i = 0; i < 2; i++) {
#pragma unroll
            for (int r = 0; r < 4; r++) {
                int row = row0 + wave * 32 + i * 16 + quad * 4 + r;
                if (row < N) {
                    float v = acc[i][j][r];
                    if (col < 40) out[(size_t)row * 40 + col] = v;
                    else          t2b[(size_t)row * 40 + (col - 40)] = f2b(v);
                }
            }
        }
    }
}

// ------------------------------------------------------------------ launch

extern "C" void kernel_launch(void* const* d_in, const int* in_sizes, int n_in,
                              void* d_out, int out_size, void* d_ws, size_t ws_size,
                              hipStream_t stream) {
    const float* x   = (const float*)d_in[0];
    const int*   src = (const int*)d_in[1];
    const int*   dst = (const int*)d_in[2];
    const float* W1s = (const float*)d_in[3];
    const float* W1n = (const float*)d_in[4];
    const float* b1  = (const float*)d_in[5];
    const float* W2s = (const float*)d_in[6];
    const float* W2n = (const float*)d_in[7];
    const float* b2  = (const float*)d_in[8];
    float* out = (float*)d_out;

    int N = in_sizes[0] / 128;
    int E = in_sizes[1];
    int nbins = (N + BIN_SIZE - 1) / BIN_SIZE;   // 782 for N=100000

    char* ws = (char*)d_ws;
    int*            row_start  = (int*)(ws + OFF_ROWSTART);
    int*            bin_cnt    = (int*)(ws + OFF_BINCNT);
    int*            bin_base   = (int*)(ws + OFF_BINBASE);
    int*            bin_cursor = (int*)(ws + OFF_BINCUR);
    unsigned int*   packed     = (unsigned int*)(ws + OFF_PACKED);
    int*            csr_src    = (int*)(ws + OFF_CSR);
    unsigned short* W1t        = (unsigned short*)(ws + OFF_W1T);
    unsigned short* W2t        = (unsigned short*)(ws + OFF_W2T);
    unsigned short* xb         = (unsigned short*)(ws + OFF_XB);
    unsigned short* aggb       = (unsigned short*)(ws + OFF_AGGB);
    unsigned short* h1b        = (unsigned short*)(ws + OFF_H1B);
    unsigned short* t2b        = (unsigned short*)(ws + OFF_T2);

    hipMemsetAsync(bin_cnt, 0, (size_t)nbins * sizeof(int), stream);

    bin_count<<<256, 256, 0, stream>>>(dst, bin_cnt, E, nbins);
    bin_scan<<<1, 1024, 0, stream>>>(bin_cnt, bin_base, bin_cursor, nbins);
    bin_scatter<<<(E + 255) / 256, 256, 0, stream>>>(src, dst, bin_cursor, packed, E);
    bin_fill<<<nbins, 256, 0, stream>>>(packed, bin_base, row_start, csr_src, N, nbins, E);

    int n8 = N * 128 / 8;
    cast_bf16<<<(n8 + 255) / 256, 256, 0, stream>>>(x, xb, n8);
    prep_w1t<<<128, 256, 0, stream>>>(W1s, W1n, W1t);
    prep_w2t<<<80, 128, 0, stream>>>(W2s, W2n, W2t);

    int aggBlocks = (N * 64 + 255) / 256;
    agg_mean_bf16<<<aggBlocks, 256, 0, stream>>>(xb, row_start, csr_src, aggb, N);
    gemm1_mfma<<<(N + 127) / 128, 256, 0, stream>>>(xb, aggb, W1t, b1, h1b, N);
    gemm2_mfma<<<(N + 127) / 128, 256, 0, stream>>>(h1b, W2t, out, t2b, N);
    agg2_add<<<aggBlocks, 256, 0, stream>>>(t2b, row_start, csr_src, b2, out, N);
}

// Round 6
// 343.270 us; speedup vs baseline: 2.0258x; 2.0258x over previous
//
#include <hip/hip_runtime.h>

// GraphSAGE 2-layer forward on MI355X.
// Round 6: CSR build via DETERMINISTIC counting sort — no global atomics.
//   Round-4 csr_fill: write-amplification-bound (107 MB lines for 6.4 MB data).
//   Round-5 bin_scatter: global-cursor contention-bound (2046 serial RMW/cursor).
//   Now: per-block LDS histograms -> hierarchical scan of hist[bin][block]
//   -> scatter at precomputed positions with LDS-only cursors.
// Rest unchanged: bf16 cast, transposed bf16 weights, MFMA 16x16x32 GEMMs,
// 2-edge/iter latency-optimized gathers, transform-then-aggregate layer 2.

typedef __attribute__((ext_vector_type(8))) short bf16x8;
typedef __attribute__((ext_vector_type(4))) float f32x4;

#define BIN_SHIFT 7
#define BIN_SIZE  128
#define NB        256          // scatter blocks (chunks)

#define OFF_ROWSTART (1ull << 20)   // 400 KB
#define OFF_HIST     (2ull << 20)   // 800 KB  hist[bin*NB + blk]
#define OFF_SCAN     (3ull << 20)   // 800 KB  scanned offsets (in-place tmp)
#define OFF_BSUMS    (4ull << 20)   // ~4 KB
#define OFF_BOFFS    ((4ull << 20) + (64ull << 10))
#define OFF_PACKED   (5ull << 20)   // 6.4 MB
#define OFF_CSR      (12ull << 20)  // 6.4 MB
#define OFF_W1T      (19ull << 20)  // 64 KB
#define OFF_W2T      (20ull << 20)  // 20 KB
#define OFF_XB       (21ull << 20)  // 25.6 MB
#define OFF_AGGB     (47ull << 20)  // 25.6 MB
#define OFF_H1B      (73ull << 20)  // 25.6 MB
#define OFF_T2       (99ull << 20)  // 8 MB (bf16)

static __device__ __forceinline__ unsigned short f2b(float f) {
    unsigned int u = __float_as_uint(f);
    u += 0x7fffu + ((u >> 16) & 1u);   // round-to-nearest-even
    return (unsigned short)(u >> 16);
}
static __device__ __forceinline__ float blo(unsigned int v) { return __uint_as_float(v << 16); }
static __device__ __forceinline__ float bhi(unsigned int v) { return __uint_as_float(v & 0xffff0000u); }

// ------------------------------------------------- CSR via counting sort

// Pass A: per-block LDS histogram of its edge chunk -> hist[bin*NB + blk].
__global__ __launch_bounds__(256) void hist_local(
    const int* __restrict__ dst, int* __restrict__ hist, int E, int nbins) {
    __shared__ int h[1024];
    int b = blockIdx.x, t = threadIdx.x;
    for (int i = t; i < nbins; i += 256) h[i] = 0;
    __syncthreads();
    int chunk = (E + NB - 1) / NB;
    int base = b * chunk;
    int lim = min(base + chunk, E);
    for (int e = base + t; e < lim; e += 256)
        atomicAdd(&h[dst[e] >> BIN_SHIFT], 1);
    __syncthreads();
    for (int i = t; i < nbins; i += 256)
        hist[i * NB + b] = h[i];
}

// Hierarchical exclusive scan over M = nbins*NB entries.
__global__ void scan1(const int* __restrict__ in, int* __restrict__ tmp,
                      int* __restrict__ bsums, int M) {
    __shared__ int s[256];
    int t = threadIdx.x;
    int i = blockIdx.x * 256 + t;
    int v = (i < M) ? in[i] : 0;
    s[t] = v;
    __syncthreads();
    for (int off = 1; off < 256; off <<= 1) {
        int u = (t >= off) ? s[t - off] : 0;
        __syncthreads();
        s[t] += u;
        __syncthreads();
    }
    if (i < M) tmp[i] = s[t] - v;
    if (t == 255) bsums[blockIdx.x] = s[t];
}

__global__ void scan2(const int* __restrict__ bsums, int* __restrict__ boffs, int nb) {
    __shared__ int s[1024];
    int t = threadIdx.x;
    int v = (t < nb) ? bsums[t] : 0;
    s[t] = v;
    __syncthreads();
    for (int off = 1; off < 1024; off <<= 1) {
        int u = (t >= off) ? s[t - off] : 0;
        __syncthreads();
        s[t] += u;
        __syncthreads();
    }
    if (t < nb) boffs[t] = s[t] - v;
}

__global__ void scan3(int* __restrict__ tmp, const int* __restrict__ boffs, int M) {
    int i = blockIdx.x * 256 + threadIdx.x;
    if (i < M) tmp[i] += boffs[blockIdx.x];
}

// Pass B: deterministic scatter. LDS cursors seeded from scanned offsets;
// zero global atomics. Each (bin,block) window is contiguous -> L2 merges.
__global__ __launch_bounds__(256) void scatter_det(
    const int* __restrict__ src, const int* __restrict__ dst,
    const int* __restrict__ scanned, unsigned int* __restrict__ packed,
    int E, int nbins) {
    __shared__ int cur[1024];
    int b = blockIdx.x, t = threadIdx.x;
    for (int i = t; i < nbins; i += 256) cur[i] = scanned[i * NB + b];
    __syncthreads();
    int chunk = (E + NB - 1) / NB;
    int base = b * chunk;
    int lim = min(base + chunk, E);
    for (int e = base + t; e < lim; e += 256) {
        int d = dst[e];
        int bin = d >> BIN_SHIFT;
        int pos = atomicAdd(&cur[bin], 1);   // LDS atomic
        packed[pos] = ((unsigned int)(d & (BIN_SIZE - 1)) << 20) | (unsigned int)src[e];
    }
}

// Pass C: one workgroup per bin -> row_start + csr_src (all windowed/local).
__global__ __launch_bounds__(256) void bin_fill(
    const unsigned int* __restrict__ packed, const int* __restrict__ scanned,
    int* __restrict__ row_start, int* __restrict__ csr_src, int N, int nbins, int E) {
    __shared__ int cnt[BIN_SIZE];
    __shared__ int pre[BIN_SIZE];
    __shared__ int ex[BIN_SIZE];
    int b = blockIdx.x;
    int t = threadIdx.x;
    int node0 = b << BIN_SHIFT;
    int beg = scanned[b * NB];
    int end = (b + 1 < nbins) ? scanned[(b + 1) * NB] : E;

    if (t < BIN_SIZE) cnt[t] = 0;
    __syncthreads();
    for (int i = beg + t; i < end; i += 256)
        atomicAdd(&cnt[packed[i] >> 20], 1);
    __syncthreads();
    if (t < BIN_SIZE) pre[t] = cnt[t];
    __syncthreads();
    for (int off = 1; off < BIN_SIZE; off <<= 1) {
        int u = (t < BIN_SIZE && t >= off) ? pre[t - off] : 0;
        __syncthreads();
        if (t < BIN_SIZE) pre[t] += u;
        __syncthreads();
    }
    if (t < BIN_SIZE) {
        ex[t] = pre[t] - cnt[t];
        int node = node0 + t;
        if (node < N) row_start[node] = beg + ex[t];
        cnt[t] = 0;   // reuse as per-node cursor
    }
    if (b == nbins - 1 && t == 0) row_start[N] = E;
    __syncthreads();
    for (int i = beg + t; i < end; i += 256) {
        unsigned int p = packed[i];
        int dl = p >> 20;
        int s = p & 0xFFFFF;
        int ofs = atomicAdd(&cnt[dl], 1);
        csr_src[beg + ex[dl] + ofs] = s;
    }
}

// ------------------------------------------------------------- prep kernels

__global__ void cast_bf16(const float* __restrict__ x, unsigned short* __restrict__ xb, int n8) {
    int i = blockIdx.x * blockDim.x + threadIdx.x;
    if (i >= n8) return;
    const float4* p = (const float4*)x + (size_t)i * 2;
    float4 v0 = p[0], v1 = p[1];
    unsigned short o[8];
    o[0] = f2b(v0.x); o[1] = f2b(v0.y); o[2] = f2b(v0.z); o[3] = f2b(v0.w);
    o[4] = f2b(v1.x); o[5] = f2b(v1.y); o[6] = f2b(v1.z); o[7] = f2b(v1.w);
    *(float4*)(xb + (size_t)i * 8) = *(float4*)o;
}

__global__ void prep_w1t(const float* __restrict__ W1s, const float* __restrict__ W1n,
                         unsigned short* __restrict__ W1t) {
    int c = blockIdx.x, k = threadIdx.x;
    float v = (k < 128) ? W1s[(size_t)k * 128 + c] : W1n[(size_t)(k - 128) * 128 + c];
    W1t[(size_t)c * 256 + k] = f2b(v);
}

__global__ void prep_w2t(const float* __restrict__ W2s, const float* __restrict__ W2n,
                         unsigned short* __restrict__ W2t) {
    int c = blockIdx.x, k = threadIdx.x;
    float v = (c < 40) ? W2s[(size_t)k * 40 + c] : W2n[(size_t)k * 40 + (c - 40)];
    W2t[(size_t)c * 128 + k] = f2b(v);
}

// ------------------------------------------------------- aggregation kernels

__global__ void agg_mean_bf16(const unsigned short* __restrict__ xb,
                              const int* __restrict__ row_start,
                              const int* __restrict__ csr_src,
                              unsigned short* __restrict__ aggb, int N) {
    int wave = (blockIdx.x * blockDim.x + threadIdx.x) >> 6;
    int lane = threadIdx.x & 63;
    if (wave >= N) return;
    int half = lane >> 5;
    int l = lane & 31;
    int beg = row_start[wave], end = row_start[wave + 1];
    const uint2* x4 = (const uint2*)xb;

    float a0 = 0.f, a1 = 0.f, a2 = 0.f, a3 = 0.f;
    int e = beg + half;
    for (; e + 2 < end; e += 4) {
        int s0 = csr_src[e];
        int s1 = csr_src[e + 2];
        uint2 v0 = x4[(size_t)s0 * 32 + l];
        uint2 v1 = x4[(size_t)s1 * 32 + l];
        a0 += blo(v0.x) + blo(v1.x);
        a1 += bhi(v0.x) + bhi(v1.x);
        a2 += blo(v0.y) + blo(v1.y);
        a3 += bhi(v0.y) + bhi(v1.y);
    }
    for (; e < end; e += 2) {
        int s = csr_src[e];
        uint2 v = x4[(size_t)s * 32 + l];
        a0 += blo(v.x); a1 += bhi(v.x); a2 += blo(v.y); a3 += bhi(v.y);
    }
    a0 += __shfl_xor(a0, 32);
    a1 += __shfl_xor(a1, 32);
    a2 += __shfl_xor(a2, 32);
    a3 += __shfl_xor(a3, 32);
    if (half == 0) {
        float inv = 1.0f / fmaxf((float)(end - beg), 1.0f);
        uint2 o;
        o.x = (unsigned int)f2b(a0 * inv) | ((unsigned int)f2b(a1 * inv) << 16);
        o.y = (unsigned int)f2b(a2 * inv) | ((unsigned int)f2b(a3 * inv) << 16);
        ((uint2*)aggb)[(size_t)wave * 32 + l] = o;
    }
}

__global__ void agg2_add(const unsigned short* __restrict__ t2b,
                         const int* __restrict__ row_start,
                         const int* __restrict__ csr_src, const float* __restrict__ b2,
                         float* __restrict__ out, int N) {
    int wave = (blockIdx.x * blockDim.x + threadIdx.x) >> 6;
    int lane = threadIdx.x & 63;
    if (wave >= N) return;
    int half = lane >> 5;
    int l = lane & 31;
    int beg = row_start[wave], end = row_start[wave + 1];
    const unsigned int* t2u = (const unsigned int*)t2b;

    float a0 = 0.f, a1 = 0.f;
    if (l < 20) {
        int e = beg + half;
        for (; e + 2 < end; e += 4) {
            int s0 = csr_src[e];
            int s1 = csr_src[e + 2];
            unsigned int v0 = t2u[(size_t)s0 * 20 + l];
            unsigned int v1 = t2u[(size_t)s1 * 20 + l];
            a0 += blo(v0) + blo(v1);
            a1 += bhi(v0) + bhi(v1);
        }
        for (; e < end; e += 2) {
            unsigned int v = t2u[(size_t)csr_src[e] * 20 + l];
            a0 += blo(v); a1 += bhi(v);
        }
    }
    a0 += __shfl_xor(a0, 32);
    a1 += __shfl_xor(a1, 32);
    if (half == 0 && l < 20) {
        float inv = 1.0f / fmaxf((float)(end - beg), 1.0f);
        float2 bb = ((const float2*)b2)[l];
        float2* op = (float2*)(out + (size_t)wave * 40 + 2 * l);
        float2 cur2 = *op;
        cur2.x += a0 * inv + bb.x;
        cur2.y += a1 * inv + bb.y;
        *op = cur2;
    }
}

// ------------------------------------------------------------------- GEMM 1

__global__ __launch_bounds__(256) void gemm1_mfma(
    const unsigned short* __restrict__ xb, const unsigned short* __restrict__ aggb,
    const unsigned short* __restrict__ W1t, const float* __restrict__ b1,
    unsigned short* __restrict__ h1, int N) {

    __shared__ unsigned short As[128 * 40];
    __shared__ unsigned short Bs[128 * 40];

    int tid = threadIdx.x;
    int wave = tid >> 6, lane = tid & 63;
    int row0 = blockIdx.x * 128;
    int m = lane & 15, quad = lane >> 4;

    f32x4 acc[2][8];
#pragma unroll
    for (int i = 0; i < 2; i++)
#pragma unroll
        for (int j = 0; j < 8; j++) acc[i][j] = (f32x4){0.f, 0.f, 0.f, 0.f};

    for (int k0 = 0; k0 < 256; k0 += 32) {
        __syncthreads();
        {
            int r = tid >> 1, kk = (tid & 1) * 16;
            int row = row0 + r;
            float4 v0 = make_float4(0, 0, 0, 0), v1 = v0;
            if (row < N) {
                const unsigned short* s = (k0 < 128)
                    ? (xb + (size_t)row * 128 + k0 + kk)
                    : (aggb + (size_t)row * 128 + (k0 - 128) + kk);
                const float4* p = (const float4*)s;
                v0 = p[0]; v1 = p[1];
            }
            *(float4*)&As[r * 40 + kk] = v0;
            *(float4*)&As[r * 40 + kk + 8] = v1;
            const float4* q = (const float4*)(W1t + (size_t)r * 256 + k0 + kk);
            float4 w0 = q[0], w1 = q[1];
            *(float4*)&Bs[r * 40 + kk] = w0;
            *(float4*)&Bs[r * 40 + kk + 8] = w1;
        }
        __syncthreads();

        bf16x8 af0 = *(bf16x8*)&As[(wave * 32 + m) * 40 + quad * 8];
        bf16x8 af1 = *(bf16x8*)&As[(wave * 32 + 16 + m) * 40 + quad * 8];
#pragma unroll
        for (int j = 0; j < 8; j++) {
            bf16x8 bfg = *(bf16x8*)&Bs[(j * 16 + m) * 40 + quad * 8];
            acc[0][j] = __builtin_amdgcn_mfma_f32_16x16x32_bf16(af0, bfg, acc[0][j], 0, 0, 0);
            acc[1][j] = __builtin_amdgcn_mfma_f32_16x16x32_bf16(af1, bfg, acc[1][j], 0, 0, 0);
        }
    }

#pragma unroll
    for (int j = 0; j < 8; j++) {
        int col = j * 16 + m;
        float bias = b1[col];
#pragma unroll
        for (int i = 0; i < 2; i++) {
#pragma unroll
            for (int r = 0; r < 4; r++) {
                int row = row0 + wave * 32 + i * 16 + quad * 4 + r;
                if (row < N) {
                    float v = fmaxf(acc[i][j][r] + bias, 0.f);
                    h1[(size_t)row * 128 + col] = f2b(v);
                }
            }
        }
    }
}

// ------------------------------------------------------------------- GEMM 2

__global__ __launch_bounds__(256) void gemm2_mfma(
    const unsigned short* __restrict__ h1, const unsigned short* __restrict__ W2t,
    float* __restrict__ out, unsigned short* __restrict__ t2b, int N) {

    __shared__ unsigned short As[128 * 40];
    __shared__ unsigned short Bs[80 * 40];

    int tid = threadIdx.x;
    int wave = tid >> 6, lane = tid & 63;
    int row0 = blockIdx.x * 128;
    int m = lane & 15, quad = lane >> 4;

    f32x4 acc[2][5];
#pragma unroll
    for (int i = 0; i < 2; i++)
#pragma unroll
        for (int j = 0; j < 5; j++) acc[i][j] = (f32x4){0.f, 0.f, 0.f, 0.f};

    for (int k0 = 0; k0 < 128; k0 += 32) {
        __syncthreads();
        {
            int r = tid >> 1, kk = (tid & 1) * 16;
            int row = row0 + r;
            float4 v0 = make_float4(0, 0, 0, 0), v1 = v0;
            if (row < N) {
                const float4* p = (const float4*)(h1 + (size_t)row * 128 + k0 + kk);
                v0 = p[0]; v1 = p[1];
            }
            *(float4*)&As[r * 40 + kk] = v0;
            *(float4*)&As[r * 40 + kk + 8] = v1;
            if (tid < 160) {
                const float4* q = (const float4*)(W2t + (size_t)r * 128 + k0 + kk);
                float4 w0 = q[0], w1 = q[1];
                *(float4*)&Bs[r * 40 + kk] = w0;
                *(float4*)&Bs[r * 40 + kk + 8] = w1;
            }
        }
        __syncthreads();

        bf16x8 af0 = *(bf16x8*)&As[(wave * 32 + m) * 40 + quad * 8];
        bf16x8 af1 = *(bf16x8*)&As[(wave * 32 + 16 + m) * 40 + quad * 8];
#pragma unroll
        for (int j = 0; j < 5; j++) {
            bf16x8 bfg = *(bf16x8*)&Bs[(j * 16 + m) * 40 + quad * 8];
            acc[0][j] = __builtin_amdgcn_mfma_f32_16x16x32_bf16(af0, bfg, acc[0][j], 0, 0, 0);
            acc[1][j] = __builtin_amdgcn_mfma_f32_16x16x32_bf16(af1, bfg, acc[1][j], 0, 0, 0);
        }
    }

#pragma unroll
    for (int j = 0; j < 5; j++) {
        int col = j * 16 + m;
#pragma unroll
        for (int i = 0; i < 2; i++) {
#pragma unroll
            for (int r = 0; r < 4; r++) {
                int row = row0 + wave * 32 + i * 16 + quad * 4 + r;
                if (row < N) {
                    float v = acc[i][j][r];
                    if (col < 40) out[(size_t)row * 40 + col] = v;
                    else          t2b[(size_t)row * 40 + (col - 40)] = f2b(v);
                }
            }
        }
    }
}

// ------------------------------------------------------------------ launch

extern "C" void kernel_launch(void* const* d_in, const int* in_sizes, int n_in,
                              void* d_out, int out_size, void* d_ws, size_t ws_size,
                              hipStream_t stream) {
    const float* x   = (const float*)d_in[0];
    const int*   src = (const int*)d_in[1];
    const int*   dst = (const int*)d_in[2];
    const float* W1s = (const float*)d_in[3];
    const float* W1n = (const float*)d_in[4];
    const float* b1  = (const float*)d_in[5];
    const float* W2s = (const float*)d_in[6];
    const float* W2n = (const float*)d_in[7];
    const float* b2  = (const float*)d_in[8];
    float* out = (float*)d_out;

    int N = in_sizes[0] / 128;
    int E = in_sizes[1];
    int nbins = (N + BIN_SIZE - 1) / BIN_SIZE;   // 782 for N=100000
    int M = nbins * NB;                          // 200192

    char* ws = (char*)d_ws;
    int*            row_start  = (int*)(ws + OFF_ROWSTART);
    int*            hist       = (int*)(ws + OFF_HIST);
    int*            scanned    = (int*)(ws + OFF_SCAN);
    int*            bsums      = (int*)(ws + OFF_BSUMS);
    int*            boffs      = (int*)(ws + OFF_BOFFS);
    unsigned int*   packed     = (unsigned int*)(ws + OFF_PACKED);
    int*            csr_src    = (int*)(ws + OFF_CSR);
    unsigned short* W1t        = (unsigned short*)(ws + OFF_W1T);
    unsigned short* W2t        = (unsigned short*)(ws + OFF_W2T);
    unsigned short* xb         = (unsigned short*)(ws + OFF_XB);
    unsigned short* aggb       = (unsigned short*)(ws + OFF_AGGB);
    unsigned short* h1b        = (unsigned short*)(ws + OFF_H1B);
    unsigned short* t2b        = (unsigned short*)(ws + OFF_T2);

    int scanBlocks = (M + 255) / 256;            // 782 <= 1024

    hist_local<<<NB, 256, 0, stream>>>(dst, hist, E, nbins);
    scan1<<<scanBlocks, 256, 0, stream>>>(hist, scanned, bsums, M);
    scan2<<<1, 1024, 0, stream>>>(bsums, boffs, scanBlocks);
    scan3<<<scanBlocks, 256, 0, stream>>>(scanned, boffs, M);
    scatter_det<<<NB, 256, 0, stream>>>(src, dst, scanned, packed, E, nbins);
    bin_fill<<<nbins, 256, 0, stream>>>(packed, scanned, row_start, csr_src, N, nbins, E);

    int n8 = N * 128 / 8;
    cast_bf16<<<(n8 + 255) / 256, 256, 0, stream>>>(x, xb, n8);
    prep_w1t<<<128, 256, 0, stream>>>(W1s, W1n, W1t);
    prep_w2t<<<80, 128, 0, stream>>>(W2s, W2n, W2t);

    int aggBlocks = (N * 64 + 255) / 256;
    agg_mean_bf16<<<aggBlocks, 256, 0, stream>>>(xb, row_start, csr_src, aggb, N);
    gemm1_mfma<<<(N + 127) / 128, 256, 0, stream>>>(xb, aggb, W1t, b1, h1b, N);
    gemm2_mfma<<<(N + 127) / 128, 256, 0, stream>>>(h1b, W2t, out, t2b, N);
    agg2_add<<<aggBlocks, 256, 0, stream>>>(t2b, row_start, csr_src, b2, out, N);
}

// Round 7
// 336.008 us; speedup vs baseline: 2.0695x; 1.0216x over previous
//
#include <hip/hip_runtime.h>

// GraphSAGE 2-layer forward on MI355X.
// Round 7: latency/VALU-optimized gathers.
//   agg_mean: quarter-wave per edge (16 lanes x uint4 = 256B row), 4 edges in
//             flight, 32-bit byte offsets (no 64-bit addr chains).
//   agg2:     t2 padded to 128B rows (fetch-line neutral, alignment win),
//             quarter-wave uint2 gathers, full 64-lane use.
// CSR build: deterministic counting sort (round 6, no global atomics).
// GEMMs: MFMA 16x16x32 bf16, transform-then-aggregate layer 2.

typedef __attribute__((ext_vector_type(8))) short bf16x8;
typedef __attribute__((ext_vector_type(4))) float f32x4;

#define BIN_SHIFT 7
#define BIN_SIZE  128
#define NB        256          // scatter blocks (chunks)

#define OFF_ROWSTART (1ull << 20)   // 400 KB
#define OFF_HIST     (2ull << 20)   // 800 KB  hist[bin*NB + blk]
#define OFF_SCAN     (3ull << 20)   // 800 KB  scanned offsets
#define OFF_BSUMS    (4ull << 20)
#define OFF_BOFFS    ((4ull << 20) + (64ull << 10))
#define OFF_PACKED   (5ull << 20)   // 6.4 MB
#define OFF_CSR      (12ull << 20)  // 6.4 MB
#define OFF_W1T      (19ull << 20)  // 64 KB
#define OFF_W2T      (20ull << 20)  // 20 KB
#define OFF_XB       (21ull << 20)  // 25.6 MB
#define OFF_AGGB     (47ull << 20)  // 25.6 MB
#define OFF_H1B      (73ull << 20)  // 25.6 MB
#define OFF_T2       (99ull << 20)  // 12.8 MB (bf16, 128B row stride)

static __device__ __forceinline__ unsigned short f2b(float f) {
    unsigned int u = __float_as_uint(f);
    u += 0x7fffu + ((u >> 16) & 1u);   // round-to-nearest-even
    return (unsigned short)(u >> 16);
}
static __device__ __forceinline__ float blo(unsigned int v) { return __uint_as_float(v << 16); }
static __device__ __forceinline__ float bhi(unsigned int v) { return __uint_as_float(v & 0xffff0000u); }

// ------------------------------------------------- CSR via counting sort

__global__ __launch_bounds__(256) void hist_local(
    const int* __restrict__ dst, int* __restrict__ hist, int E, int nbins) {
    __shared__ int h[1024];
    int b = blockIdx.x, t = threadIdx.x;
    for (int i = t; i < nbins; i += 256) h[i] = 0;
    __syncthreads();
    int chunk = (E + NB - 1) / NB;
    int base = b * chunk;
    int lim = min(base + chunk, E);
    for (int e = base + t; e < lim; e += 256)
        atomicAdd(&h[dst[e] >> BIN_SHIFT], 1);
    __syncthreads();
    for (int i = t; i < nbins; i += 256)
        hist[i * NB + b] = h[i];
}

__global__ void scan1(const int* __restrict__ in, int* __restrict__ tmp,
                      int* __restrict__ bsums, int M) {
    __shared__ int s[256];
    int t = threadIdx.x;
    int i = blockIdx.x * 256 + t;
    int v = (i < M) ? in[i] : 0;
    s[t] = v;
    __syncthreads();
    for (int off = 1; off < 256; off <<= 1) {
        int u = (t >= off) ? s[t - off] : 0;
        __syncthreads();
        s[t] += u;
        __syncthreads();
    }
    if (i < M) tmp[i] = s[t] - v;
    if (t == 255) bsums[blockIdx.x] = s[t];
}

__global__ void scan2(const int* __restrict__ bsums, int* __restrict__ boffs, int nb) {
    __shared__ int s[1024];
    int t = threadIdx.x;
    int v = (t < nb) ? bsums[t] : 0;
    s[t] = v;
    __syncthreads();
    for (int off = 1; off < 1024; off <<= 1) {
        int u = (t >= off) ? s[t - off] : 0;
        __syncthreads();
        s[t] += u;
        __syncthreads();
    }
    if (t < nb) boffs[t] = s[t] - v;
}

__global__ void scan3(int* __restrict__ tmp, const int* __restrict__ boffs, int M) {
    int i = blockIdx.x * 256 + threadIdx.x;
    if (i < M) tmp[i] += boffs[blockIdx.x];
}

__global__ __launch_bounds__(256) void scatter_det(
    const int* __restrict__ src, const int* __restrict__ dst,
    const int* __restrict__ scanned, unsigned int* __restrict__ packed,
    int E, int nbins) {
    __shared__ int cur[1024];
    int b = blockIdx.x, t = threadIdx.x;
    for (int i = t; i < nbins; i += 256) cur[i] = scanned[i * NB + b];
    __syncthreads();
    int chunk = (E + NB - 1) / NB;
    int base = b * chunk;
    int lim = min(base + chunk, E);
    for (int e = base + t; e < lim; e += 256) {
        int d = dst[e];
        int bin = d >> BIN_SHIFT;
        int pos = atomicAdd(&cur[bin], 1);   // LDS atomic
        packed[pos] = ((unsigned int)(d & (BIN_SIZE - 1)) << 20) | (unsigned int)src[e];
    }
}

__global__ __launch_bounds__(256) void bin_fill(
    const unsigned int* __restrict__ packed, const int* __restrict__ scanned,
    int* __restrict__ row_start, int* __restrict__ csr_src, int N, int nbins, int E) {
    __shared__ int cnt[BIN_SIZE];
    __shared__ int pre[BIN_SIZE];
    __shared__ int ex[BIN_SIZE];
    int b = blockIdx.x;
    int t = threadIdx.x;
    int node0 = b << BIN_SHIFT;
    int beg = scanned[b * NB];
    int end = (b + 1 < nbins) ? scanned[(b + 1) * NB] : E;

    if (t < BIN_SIZE) cnt[t] = 0;
    __syncthreads();
    for (int i = beg + t; i < end; i += 256)
        atomicAdd(&cnt[packed[i] >> 20], 1);
    __syncthreads();
    if (t < BIN_SIZE) pre[t] = cnt[t];
    __syncthreads();
    for (int off = 1; off < BIN_SIZE; off <<= 1) {
        int u = (t < BIN_SIZE && t >= off) ? pre[t - off] : 0;
        __syncthreads();
        if (t < BIN_SIZE) pre[t] += u;
        __syncthreads();
    }
    if (t < BIN_SIZE) {
        ex[t] = pre[t] - cnt[t];
        int node = node0 + t;
        if (node < N) row_start[node] = beg + ex[t];
        cnt[t] = 0;
    }
    if (b == nbins - 1 && t == 0) row_start[N] = E;
    __syncthreads();
    for (int i = beg + t; i < end; i += 256) {
        unsigned int p = packed[i];
        int dl = p >> 20;
        int s = p & 0xFFFFF;
        int ofs = atomicAdd(&cnt[dl], 1);
        csr_src[beg + ex[dl] + ofs] = s;
    }
}

// ------------------------------------------------------------- prep kernels

__global__ void cast_bf16(const float* __restrict__ x, unsigned short* __restrict__ xb, int n8) {
    int i = blockIdx.x * blockDim.x + threadIdx.x;
    if (i >= n8) return;
    const float4* p = (const float4*)x + (size_t)i * 2;
    float4 v0 = p[0], v1 = p[1];
    unsigned short o[8];
    o[0] = f2b(v0.x); o[1] = f2b(v0.y); o[2] = f2b(v0.z); o[3] = f2b(v0.w);
    o[4] = f2b(v1.x); o[5] = f2b(v1.y); o[6] = f2b(v1.z); o[7] = f2b(v1.w);
    *(float4*)(xb + (size_t)i * 8) = *(float4*)o;
}

__global__ void prep_w1t(const float* __restrict__ W1s, const float* __restrict__ W1n,
                         unsigned short* __restrict__ W1t) {
    int c = blockIdx.x, k = threadIdx.x;
    float v = (k < 128) ? W1s[(size_t)k * 128 + c] : W1n[(size_t)(k - 128) * 128 + c];
    W1t[(size_t)c * 256 + k] = f2b(v);
}

__global__ void prep_w2t(const float* __restrict__ W2s, const float* __restrict__ W2n,
                         unsigned short* __restrict__ W2t) {
    int c = blockIdx.x, k = threadIdx.x;
    float v = (c < 40) ? W2s[(size_t)k * 40 + c] : W2n[(size_t)k * 40 + (c - 40)];
    W2t[(size_t)c * 128 + k] = f2b(v);
}

// ------------------------------------------------------- aggregation kernels

// One wave per node. Quarter q handles edges e+4q..e+4q+3 (body of 16).
// Lane-in-quarter l owns dims [8l, 8l+8) via one uint4 (16B) -> 4 independent
// 16B gathers in flight per lane. All byte offsets 32-bit.
__global__ void agg_mean_bf16(const unsigned short* __restrict__ xb,
                              const int* __restrict__ row_start,
                              const int* __restrict__ csr_src,
                              unsigned short* __restrict__ aggb, int N) {
    int wave = (blockIdx.x * blockDim.x + threadIdx.x) >> 6;
    int lane = threadIdx.x & 63;
    if (wave >= N) return;
    int q = lane >> 4;
    int l = lane & 15;
    int beg = row_start[wave], end = row_start[wave + 1];
    const char* xbase = (const char*)xb;
    unsigned loff = (unsigned)l << 4;

    float a0 = 0.f, a1 = 0.f, a2 = 0.f, a3 = 0.f;
    float a4 = 0.f, a5 = 0.f, a6 = 0.f, a7 = 0.f;

    int e = beg;
    for (; e + 16 <= end; e += 16) {
        int eq = e + 4 * q;
        int s0 = csr_src[eq + 0];
        int s1 = csr_src[eq + 1];
        int s2 = csr_src[eq + 2];
        int s3 = csr_src[eq + 3];
        uint4 v0 = *(const uint4*)(xbase + (((unsigned)s0 << 8) + loff));
        uint4 v1 = *(const uint4*)(xbase + (((unsigned)s1 << 8) + loff));
        uint4 v2 = *(const uint4*)(xbase + (((unsigned)s2 << 8) + loff));
        uint4 v3 = *(const uint4*)(xbase + (((unsigned)s3 << 8) + loff));
        a0 += blo(v0.x) + blo(v1.x) + blo(v2.x) + blo(v3.x);
        a1 += bhi(v0.x) + bhi(v1.x) + bhi(v2.x) + bhi(v3.x);
        a2 += blo(v0.y) + blo(v1.y) + blo(v2.y) + blo(v3.y);
        a3 += bhi(v0.y) + bhi(v1.y) + bhi(v2.y) + bhi(v3.y);
        a4 += blo(v0.z) + blo(v1.z) + blo(v2.z) + blo(v3.z);
        a5 += bhi(v0.z) + bhi(v1.z) + bhi(v2.z) + bhi(v3.z);
        a6 += blo(v0.w) + blo(v1.w) + blo(v2.w) + blo(v3.w);
        a7 += bhi(v0.w) + bhi(v1.w) + bhi(v2.w) + bhi(v3.w);
    }
    for (; e + 4 <= end; e += 4) {
        int s = csr_src[e + q];
        uint4 v = *(const uint4*)(xbase + (((unsigned)s << 8) + loff));
        a0 += blo(v.x); a1 += bhi(v.x); a2 += blo(v.y); a3 += bhi(v.y);
        a4 += blo(v.z); a5 += bhi(v.z); a6 += blo(v.w); a7 += bhi(v.w);
    }
    int rem = end - e;
    if (q < rem) {
        int s = csr_src[e + q];
        uint4 v = *(const uint4*)(xbase + (((unsigned)s << 8) + loff));
        a0 += blo(v.x); a1 += bhi(v.x); a2 += blo(v.y); a3 += bhi(v.y);
        a4 += blo(v.z); a5 += bhi(v.z); a6 += blo(v.w); a7 += bhi(v.w);
    }
    // reduce across quarters
    a0 += __shfl_xor(a0, 16); a0 += __shfl_xor(a0, 32);
    a1 += __shfl_xor(a1, 16); a1 += __shfl_xor(a1, 32);
    a2 += __shfl_xor(a2, 16); a2 += __shfl_xor(a2, 32);
    a3 += __shfl_xor(a3, 16); a3 += __shfl_xor(a3, 32);
    a4 += __shfl_xor(a4, 16); a4 += __shfl_xor(a4, 32);
    a5 += __shfl_xor(a5, 16); a5 += __shfl_xor(a5, 32);
    a6 += __shfl_xor(a6, 16); a6 += __shfl_xor(a6, 32);
    a7 += __shfl_xor(a7, 16); a7 += __shfl_xor(a7, 32);
    if (q == 0) {
        float inv = 1.0f / fmaxf((float)(end - beg), 1.0f);
        uint4 o;
        o.x = (unsigned int)f2b(a0 * inv) | ((unsigned int)f2b(a1 * inv) << 16);
        o.y = (unsigned int)f2b(a2 * inv) | ((unsigned int)f2b(a3 * inv) << 16);
        o.z = (unsigned int)f2b(a4 * inv) | ((unsigned int)f2b(a5 * inv) << 16);
        o.w = (unsigned int)f2b(a6 * inv) | ((unsigned int)f2b(a7 * inv) << 16);
        *(uint4*)((char*)aggb + (((unsigned)wave << 8) + loff)) = o;
    }
}

// One wave per node over bf16 t2 (padded 128B rows: dims 0..39 real, 40..63
// zero). Quarter q: edges e+4q..e+4q+3; lane l owns dims [4l, 4l+4) (uint2).
__global__ void agg2_add(const unsigned short* __restrict__ t2b,
                         const int* __restrict__ row_start,
                         const int* __restrict__ csr_src, const float* __restrict__ b2,
                         float* __restrict__ out, int N) {
    int wave = (blockIdx.x * blockDim.x + threadIdx.x) >> 6;
    int lane = threadIdx.x & 63;
    if (wave >= N) return;
    int q = lane >> 4;
    int l = lane & 15;
    int beg = row_start[wave], end = row_start[wave + 1];
    const char* tbase = (const char*)t2b;
    unsigned loff = (unsigned)l << 3;

    float a0 = 0.f, a1 = 0.f, a2 = 0.f, a3 = 0.f;

    int e = beg;
    for (; e + 16 <= end; e += 16) {
        int eq = e + 4 * q;
        int s0 = csr_src[eq + 0];
        int s1 = csr_src[eq + 1];
        int s2 = csr_src[eq + 2];
        int s3 = csr_src[eq + 3];
        uint2 v0 = *(const uint2*)(tbase + (((unsigned)s0 << 7) + loff));
        uint2 v1 = *(const uint2*)(tbase + (((unsigned)s1 << 7) + loff));
        uint2 v2 = *(const uint2*)(tbase + (((unsigned)s2 << 7) + loff));
        uint2 v3 = *(const uint2*)(tbase + (((unsigned)s3 << 7) + loff));
        a0 += blo(v0.x) + blo(v1.x) + blo(v2.x) + blo(v3.x);
        a1 += bhi(v0.x) + bhi(v1.x) + bhi(v2.x) + bhi(v3.x);
        a2 += blo(v0.y) + blo(v1.y) + blo(v2.y) + blo(v3.y);
        a3 += bhi(v0.y) + bhi(v1.y) + bhi(v2.y) + bhi(v3.y);
    }
    for (; e + 4 <= end; e += 4) {
        int s = csr_src[e + q];
        uint2 v = *(const uint2*)(tbase + (((unsigned)s << 7) + loff));
        a0 += blo(v.x); a1 += bhi(v.x); a2 += blo(v.y); a3 += bhi(v.y);
    }
    int rem = end - e;
    if (q < rem) {
        int s = csr_src[e + q];
        uint2 v = *(const uint2*)(tbase + (((unsigned)s << 7) + loff));
        a0 += blo(v.x); a1 += bhi(v.x); a2 += blo(v.y); a3 += bhi(v.y);
    }
    a0 += __shfl_xor(a0, 16); a0 += __shfl_xor(a0, 32);
    a1 += __shfl_xor(a1, 16); a1 += __shfl_xor(a1, 32);
    a2 += __shfl_xor(a2, 16); a2 += __shfl_xor(a2, 32);
    a3 += __shfl_xor(a3, 16); a3 += __shfl_xor(a3, 32);
    if (q == 0 && l < 10) {
        float inv = 1.0f / fmaxf((float)(end - beg), 1.0f);
        float4 bb = ((const float4*)b2)[l];
        float4* op = (float4*)((char*)out + ((unsigned)wave * 160u + ((unsigned)l << 4)));
        float4 cur = *op;
        cur.x += a0 * inv + bb.x;
        cur.y += a1 * inv + bb.y;
        cur.z += a2 * inv + bb.z;
        cur.w += a3 * inv + bb.w;
        *op = cur;
    }
}

// ------------------------------------------------------------------- GEMM 1

__global__ __launch_bounds__(256) void gemm1_mfma(
    const unsigned short* __restrict__ xb, const unsigned short* __restrict__ aggb,
    const unsigned short* __restrict__ W1t, const float* __restrict__ b1,
    unsigned short* __restrict__ h1, int N) {

    __shared__ unsigned short As[128 * 40];
    __shared__ unsigned short Bs[128 * 40];

    int tid = threadIdx.x;
    int wave = tid >> 6, lane = tid & 63;
    int row0 = blockIdx.x * 128;
    int m = lane & 15, quad = lane >> 4;

    f32x4 acc[2][8];
#pragma unroll
    for (int i = 0; i < 2; i++)
#pragma unroll
        for (int j = 0; j < 8; j++) acc[i][j] = (f32x4){0.f, 0.f, 0.f, 0.f};

    for (int k0 = 0; k0 < 256; k0 += 32) {
        __syncthreads();
        {
            int r = tid >> 1, kk = (tid & 1) * 16;
            int row = row0 + r;
            float4 v0 = make_float4(0, 0, 0, 0), v1 = v0;
            if (row < N) {
                const unsigned short* s = (k0 < 128)
                    ? (xb + (size_t)row * 128 + k0 + kk)
                    : (aggb + (size_t)row * 128 + (k0 - 128) + kk);
                const float4* p = (const float4*)s;
                v0 = p[0]; v1 = p[1];
            }
            *(float4*)&As[r * 40 + kk] = v0;
            *(float4*)&As[r * 40 + kk + 8] = v1;
            const float4* q2 = (const float4*)(W1t + (size_t)r * 256 + k0 + kk);
            float4 w0 = q2[0], w1 = q2[1];
            *(float4*)&Bs[r * 40 + kk] = w0;
            *(float4*)&Bs[r * 40 + kk + 8] = w1;
        }
        __syncthreads();

        bf16x8 af0 = *(bf16x8*)&As[(wave * 32 + m) * 40 + quad * 8];
        bf16x8 af1 = *(bf16x8*)&As[(wave * 32 + 16 + m) * 40 + quad * 8];
#pragma unroll
        for (int j = 0; j < 8; j++) {
            bf16x8 bfg = *(bf16x8*)&Bs[(j * 16 + m) * 40 + quad * 8];
            acc[0][j] = __builtin_amdgcn_mfma_f32_16x16x32_bf16(af0, bfg, acc[0][j], 0, 0, 0);
            acc[1][j] = __builtin_amdgcn_mfma_f32_16x16x32_bf16(af1, bfg, acc[1][j], 0, 0, 0);
        }
    }

#pragma unroll
    for (int j = 0; j < 8; j++) {
        int col = j * 16 + m;
        float bias = b1[col];
#pragma unroll
        for (int i = 0; i < 2; i++) {
#pragma unroll
            for (int r = 0; r < 4; r++) {
                int row = row0 + wave * 32 + i * 16 + quad * 4 + r;
                if (row < N) {
                    float v = fmaxf(acc[i][j][r] + bias, 0.f);
                    h1[(size_t)row * 128 + col] = f2b(v);
                }
            }
        }
    }
}

// ------------------------------------------------------------------- GEMM 2
// [out_self | t2(bf16, stride 64)] = h1 @ W2cat; K=128, 80 fused cols.

__global__ __launch_bounds__(256) void gemm2_mfma(
    const unsigned short* __restrict__ h1, const unsigned short* __restrict__ W2t,
    float* __restrict__ out, unsigned short* __restrict__ t2b, int N) {

    __shared__ unsigned short As[128 * 40];
    __shared__ unsigned short Bs[80 * 40];

    int tid = threadIdx.x;
    int wave = tid >> 6, lane = tid & 63;
    int row0 = blockIdx.x * 128;
    int m = lane & 15, quad = lane >> 4;

    f32x4 acc[2][5];
#pragma unroll
    for (int i = 0; i < 2; i++)
#pragma unroll
        for (int j = 0; j < 5; j++) acc[i][j] = (f32x4){0.f, 0.f, 0.f, 0.f};

    for (int k0 = 0; k0 < 128; k0 += 32) {
        __syncthreads();
        {
            int r = tid >> 1, kk = (tid & 1) * 16;
            int row = row0 + r;
            float4 v0 = make_float4(0, 0, 0, 0), v1 = v0;
            if (row < N) {
                const float4* p = (const float4*)(h1 + (size_t)row * 128 + k0 + kk);
                v0 = p[0]; v1 = p[1];
            }
            *(float4*)&As[r * 40 + kk] = v0;
            *(float4*)&As[r * 40 + kk + 8] = v1;
            if (tid < 160) {
                const float4* q2 = (const float4*)(W2t + (size_t)r * 128 + k0 + kk);
                float4 w0 = q2[0], w1 = q2[1];
                *(float4*)&Bs[r * 40 + kk] = w0;
                *(float4*)&Bs[r * 40 + kk + 8] = w1;
            }
        }
        __syncthreads();

        bf16x8 af0 = *(bf16x8*)&As[(wave * 32 + m) * 40 + quad * 8];
        bf16x8 af1 = *(bf16x8*)&As[(wave * 32 + 16 + m) * 40 + quad * 8];
#pragma unroll
        for (int j = 0; j < 5; j++) {
            bf16x8 bfg = *(bf16x8*)&Bs[(j * 16 + m) * 40 + quad * 8];
            acc[0][j] = __builtin_amdgcn_mfma_f32_16x16x32_bf16(af0, bfg, acc[0][j], 0, 0, 0);
            acc[1][j] = __builtin_amdgcn_mfma_f32_16x16x32_bf16(af1, bfg, acc[1][j], 0, 0, 0);
        }
    }

#pragma unroll
    for (int j = 0; j < 5; j++) {
        int col = j * 16 + m;
#pragma unroll
        for (int i = 0; i < 2; i++) {
#pragma unroll
            for (int r = 0; r < 4; r++) {
                int row = row0 + wave * 32 + i * 16 + quad * 4 + r;
                if (row < N) {
                    float v = acc[i][j][r];
                    if (col < 40) out[(size_t)row * 40 + col] = v;
                    else          t2b[(size_t)row * 64 + (col - 40)] = f2b(v);
                }
            }
        }
    }
}

// ------------------------------------------------------------------ launch

extern "C" void kernel_launch(void* const* d_in, const int* in_sizes, int n_in,
                              void* d_out, int out_size, void* d_ws, size_t ws_size,
                              hipStream_t stream) {
    const float* x   = (const float*)d_in[0];
    const int*   src = (const int*)d_in[1];
    const int*   dst = (const int*)d_in[2];
    const float* W1s = (const float*)d_in[3];
    const float* W1n = (const float*)d_in[4];
    const float* b1  = (const float*)d_in[5];
    const float* W2s = (const float*)d_in[6];
    const float* W2n = (const float*)d_in[7];
    const float* b2  = (const float*)d_in[8];
    float* out = (float*)d_out;

    int N = in_sizes[0] / 128;
    int E = in_sizes[1];
    int nbins = (N + BIN_SIZE - 1) / BIN_SIZE;   // 782 for N=100000
    int M = nbins * NB;

    char* ws = (char*)d_ws;
    int*            row_start  = (int*)(ws + OFF_ROWSTART);
    int*            hist       = (int*)(ws + OFF_HIST);
    int*            scanned    = (int*)(ws + OFF_SCAN);
    int*            bsums      = (int*)(ws + OFF_BSUMS);
    int*            boffs      = (int*)(ws + OFF_BOFFS);
    unsigned int*   packed     = (unsigned int*)(ws + OFF_PACKED);
    int*            csr_src    = (int*)(ws + OFF_CSR);
    unsigned short* W1t        = (unsigned short*)(ws + OFF_W1T);
    unsigned short* W2t        = (unsigned short*)(ws + OFF_W2T);
    unsigned short* xb         = (unsigned short*)(ws + OFF_XB);
    unsigned short* aggb       = (unsigned short*)(ws + OFF_AGGB);
    unsigned short* h1b        = (unsigned short*)(ws + OFF_H1B);
    unsigned short* t2b        = (unsigned short*)(ws + OFF_T2);

    int scanBlocks = (M + 255) / 256;

    hist_local<<<NB, 256, 0, stream>>>(dst, hist, E, nbins);
    scan1<<<scanBlocks, 256, 0, stream>>>(hist, scanned, bsums, M);
    scan2<<<1, 1024, 0, stream>>>(bsums, boffs, scanBlocks);
    scan3<<<scanBlocks, 256, 0, stream>>>(scanned, boffs, M);
    scatter_det<<<NB, 256, 0, stream>>>(src, dst, scanned, packed, E, nbins);
    bin_fill<<<nbins, 256, 0, stream>>>(packed, scanned, row_start, csr_src, N, nbins, E);

    int n8 = N * 128 / 8;
    cast_bf16<<<(n8 + 255) / 256, 256, 0, stream>>>(x, xb, n8);
    prep_w1t<<<128, 256, 0, stream>>>(W1s, W1n, W1t);
    prep_w2t<<<80, 128, 0, stream>>>(W2s, W2n, W2t);

    // zero t2 pad columns (rows padded to 64 bf16)
    hipMemsetAsync(t2b, 0, (size_t)N * 64 * sizeof(unsigned short), stream);

    int aggBlocks = (N * 64 + 255) / 256;
    agg_mean_bf16<<<aggBlocks, 256, 0, stream>>>(xb, row_start, csr_src, aggb, N);
    gemm1_mfma<<<(N + 127) / 128, 256, 0, stream>>>(xb, aggb, W1t, b1, h1b, N);
    gemm2_mfma<<<(N + 127) / 128, 256, 0, stream>>>(h1b, W2t, out, t2b, N);
    agg2_add<<<aggBlocks, 256, 0, stream>>>(t2b, row_start, csr_src, b2, out, N);
}

// Round 8
// 306.924 us; speedup vs baseline: 2.2656x; 1.0948x over previous
//
#include <hip/hip_runtime.h>

// GraphSAGE 2-layer forward on MI355X.
// Round 8: phase elimination.
//   gemm12: fused layer-1 + layer-2 transform. h1 tile stays in LDS
//           (128x136-stride bf16); W2t preloaded once. Kills the 51 MB
//           h1 global roundtrip + one dispatch.
//   t2 split: t2lo (dims 0-31, 64B rows, 6.4 MB) + t2hi (dims 32-39,
//           16B rows, 1.6 MB ~L2-resident) -> agg2 fetches ~1 line/edge.
//   prep_weights: merged W1t/W2t transpose kernel.
// CSR: deterministic counting sort (round 6). agg_mean: round-7 quarter-wave
// gather (near its L2/L3-service floor).

typedef __attribute__((ext_vector_type(8))) short bf16x8;
typedef __attribute__((ext_vector_type(4))) float f32x4;

#define BIN_SHIFT 7
#define BIN_SIZE  128
#define NB        256          // scatter blocks (chunks)

#define OFF_ROWSTART (1ull << 20)   // 400 KB
#define OFF_HIST     (2ull << 20)   // 800 KB  hist[bin*NB + blk]
#define OFF_SCAN     (3ull << 20)   // 800 KB
#define OFF_BSUMS    (4ull << 20)
#define OFF_BOFFS    ((4ull << 20) + (64ull << 10))
#define OFF_PACKED   (5ull << 20)   // 6.4 MB
#define OFF_CSR      (12ull << 20)  // 6.4 MB
#define OFF_W1T      (19ull << 20)  // 64 KB
#define OFF_W2T      (20ull << 20)  // 20 KB
#define OFF_XB       (21ull << 20)  // 25.6 MB
#define OFF_AGGB     (47ull << 20)  // 25.6 MB
#define OFF_T2LO     (73ull << 20)  // 6.4 MB  (32 bf16/row)
#define OFF_T2HI     (80ull << 20)  // 1.6 MB  (8 bf16/row)

static __device__ __forceinline__ unsigned short f2b(float f) {
    unsigned int u = __float_as_uint(f);
    u += 0x7fffu + ((u >> 16) & 1u);   // round-to-nearest-even
    return (unsigned short)(u >> 16);
}
static __device__ __forceinline__ float blo(unsigned int v) { return __uint_as_float(v << 16); }
static __device__ __forceinline__ float bhi(unsigned int v) { return __uint_as_float(v & 0xffff0000u); }

// ------------------------------------------------- CSR via counting sort

__global__ __launch_bounds__(256) void hist_local(
    const int* __restrict__ dst, int* __restrict__ hist, int E, int nbins) {
    __shared__ int h[1024];
    int b = blockIdx.x, t = threadIdx.x;
    for (int i = t; i < nbins; i += 256) h[i] = 0;
    __syncthreads();
    int chunk = (E + NB - 1) / NB;
    int base = b * chunk;
    int lim = min(base + chunk, E);
    for (int e = base + t; e < lim; e += 256)
        atomicAdd(&h[dst[e] >> BIN_SHIFT], 1);
    __syncthreads();
    for (int i = t; i < nbins; i += 256)
        hist[i * NB + b] = h[i];
}

__global__ void scan1(const int* __restrict__ in, int* __restrict__ tmp,
                      int* __restrict__ bsums, int M) {
    __shared__ int s[256];
    int t = threadIdx.x;
    int i = blockIdx.x * 256 + t;
    int v = (i < M) ? in[i] : 0;
    s[t] = v;
    __syncthreads();
    for (int off = 1; off < 256; off <<= 1) {
        int u = (t >= off) ? s[t - off] : 0;
        __syncthreads();
        s[t] += u;
        __syncthreads();
    }
    if (i < M) tmp[i] = s[t] - v;
    if (t == 255) bsums[blockIdx.x] = s[t];
}

__global__ void scan2(const int* __restrict__ bsums, int* __restrict__ boffs, int nb) {
    __shared__ int s[1024];
    int t = threadIdx.x;
    int v = (t < nb) ? bsums[t] : 0;
    s[t] = v;
    __syncthreads();
    for (int off = 1; off < 1024; off <<= 1) {
        int u = (t >= off) ? s[t - off] : 0;
        __syncthreads();
        s[t] += u;
        __syncthreads();
    }
    if (t < nb) boffs[t] = s[t] - v;
}

__global__ void scan3(int* __restrict__ tmp, const int* __restrict__ boffs, int M) {
    int i = blockIdx.x * 256 + threadIdx.x;
    if (i < M) tmp[i] += boffs[blockIdx.x];
}

__global__ __launch_bounds__(256) void scatter_det(
    const int* __restrict__ src, const int* __restrict__ dst,
    const int* __restrict__ scanned, unsigned int* __restrict__ packed,
    int E, int nbins) {
    __shared__ int cur[1024];
    int b = blockIdx.x, t = threadIdx.x;
    for (int i = t; i < nbins; i += 256) cur[i] = scanned[i * NB + b];
    __syncthreads();
    int chunk = (E + NB - 1) / NB;
    int base = b * chunk;
    int lim = min(base + chunk, E);
    for (int e = base + t; e < lim; e += 256) {
        int d = dst[e];
        int bin = d >> BIN_SHIFT;
        int pos = atomicAdd(&cur[bin], 1);   // LDS atomic
        packed[pos] = ((unsigned int)(d & (BIN_SIZE - 1)) << 20) | (unsigned int)src[e];
    }
}

__global__ __launch_bounds__(256) void bin_fill(
    const unsigned int* __restrict__ packed, const int* __restrict__ scanned,
    int* __restrict__ row_start, int* __restrict__ csr_src, int N, int nbins, int E) {
    __shared__ int cnt[BIN_SIZE];
    __shared__ int pre[BIN_SIZE];
    __shared__ int ex[BIN_SIZE];
    int b = blockIdx.x;
    int t = threadIdx.x;
    int node0 = b << BIN_SHIFT;
    int beg = scanned[b * NB];
    int end = (b + 1 < nbins) ? scanned[(b + 1) * NB] : E;

    if (t < BIN_SIZE) cnt[t] = 0;
    __syncthreads();
    for (int i = beg + t; i < end; i += 256)
        atomicAdd(&cnt[packed[i] >> 20], 1);
    __syncthreads();
    if (t < BIN_SIZE) pre[t] = cnt[t];
    __syncthreads();
    for (int off = 1; off < BIN_SIZE; off <<= 1) {
        int u = (t < BIN_SIZE && t >= off) ? pre[t - off] : 0;
        __syncthreads();
        if (t < BIN_SIZE) pre[t] += u;
        __syncthreads();
    }
    if (t < BIN_SIZE) {
        ex[t] = pre[t] - cnt[t];
        int node = node0 + t;
        if (node < N) row_start[node] = beg + ex[t];
        cnt[t] = 0;
    }
    if (b == nbins - 1 && t == 0) row_start[N] = E;
    __syncthreads();
    for (int i = beg + t; i < end; i += 256) {
        unsigned int p = packed[i];
        int dl = p >> 20;
        int s = p & 0xFFFFF;
        int ofs = atomicAdd(&cnt[dl], 1);
        csr_src[beg + ex[dl] + ofs] = s;
    }
}

// ------------------------------------------------------------- prep kernels

__global__ void cast_bf16(const float* __restrict__ x, unsigned short* __restrict__ xb, int n8) {
    int i = blockIdx.x * blockDim.x + threadIdx.x;
    if (i >= n8) return;
    const float4* p = (const float4*)x + (size_t)i * 2;
    float4 v0 = p[0], v1 = p[1];
    unsigned short o[8];
    o[0] = f2b(v0.x); o[1] = f2b(v0.y); o[2] = f2b(v0.z); o[3] = f2b(v0.w);
    o[4] = f2b(v1.x); o[5] = f2b(v1.y); o[6] = f2b(v1.z); o[7] = f2b(v1.w);
    *(float4*)(xb + (size_t)i * 8) = *(float4*)o;
}

// blocks 0..127: W1t col; blocks 128..207: W2t col.
__global__ void prep_weights(const float* __restrict__ W1s, const float* __restrict__ W1n,
                             const float* __restrict__ W2s, const float* __restrict__ W2n,
                             unsigned short* __restrict__ W1t, unsigned short* __restrict__ W2t) {
    int blk = blockIdx.x, k = threadIdx.x;
    if (blk < 128) {
        int c = blk;
        float v = (k < 128) ? W1s[(size_t)k * 128 + c] : W1n[(size_t)(k - 128) * 128 + c];
        W1t[(size_t)c * 256 + k] = f2b(v);
    } else if (k < 128) {
        int c = blk - 128;
        float v = (c < 40) ? W2s[(size_t)k * 40 + c] : W2n[(size_t)k * 40 + (c - 40)];
        W2t[(size_t)c * 128 + k] = f2b(v);
    }
}

// ------------------------------------------------------- aggregation kernels

// One wave per node; quarter q handles edges e+4q..e+4q+3; lane-in-quarter l
// owns dims [8l, 8l+8) via uint4. 32-bit byte offsets.
__global__ void agg_mean_bf16(const unsigned short* __restrict__ xb,
                              const int* __restrict__ row_start,
                              const int* __restrict__ csr_src,
                              unsigned short* __restrict__ aggb, int N) {
    int wave = (blockIdx.x * blockDim.x + threadIdx.x) >> 6;
    int lane = threadIdx.x & 63;
    if (wave >= N) return;
    int q = lane >> 4;
    int l = lane & 15;
    int beg = row_start[wave], end = row_start[wave + 1];
    const char* xbase = (const char*)xb;
    unsigned loff = (unsigned)l << 4;

    float a0 = 0.f, a1 = 0.f, a2 = 0.f, a3 = 0.f;
    float a4 = 0.f, a5 = 0.f, a6 = 0.f, a7 = 0.f;

    int e = beg;
    for (; e + 16 <= end; e += 16) {
        int eq = e + 4 * q;
        int s0 = csr_src[eq + 0];
        int s1 = csr_src[eq + 1];
        int s2 = csr_src[eq + 2];
        int s3 = csr_src[eq + 3];
        uint4 v0 = *(const uint4*)(xbase + (((unsigned)s0 << 8) + loff));
        uint4 v1 = *(const uint4*)(xbase + (((unsigned)s1 << 8) + loff));
        uint4 v2 = *(const uint4*)(xbase + (((unsigned)s2 << 8) + loff));
        uint4 v3 = *(const uint4*)(xbase + (((unsigned)s3 << 8) + loff));
        a0 += blo(v0.x) + blo(v1.x) + blo(v2.x) + blo(v3.x);
        a1 += bhi(v0.x) + bhi(v1.x) + bhi(v2.x) + bhi(v3.x);
        a2 += blo(v0.y) + blo(v1.y) + blo(v2.y) + blo(v3.y);
        a3 += bhi(v0.y) + bhi(v1.y) + bhi(v2.y) + bhi(v3.y);
        a4 += blo(v0.z) + blo(v1.z) + blo(v2.z) + blo(v3.z);
        a5 += bhi(v0.z) + bhi(v1.z) + bhi(v2.z) + bhi(v3.z);
        a6 += blo(v0.w) + blo(v1.w) + blo(v2.w) + blo(v3.w);
        a7 += bhi(v0.w) + bhi(v1.w) + bhi(v2.w) + bhi(v3.w);
    }
    for (; e + 4 <= end; e += 4) {
        int s = csr_src[e + q];
        uint4 v = *(const uint4*)(xbase + (((unsigned)s << 8) + loff));
        a0 += blo(v.x); a1 += bhi(v.x); a2 += blo(v.y); a3 += bhi(v.y);
        a4 += blo(v.z); a5 += bhi(v.z); a6 += blo(v.w); a7 += bhi(v.w);
    }
    int rem = end - e;
    if (q < rem) {
        int s = csr_src[e + q];
        uint4 v = *(const uint4*)(xbase + (((unsigned)s << 8) + loff));
        a0 += blo(v.x); a1 += bhi(v.x); a2 += blo(v.y); a3 += bhi(v.y);
        a4 += blo(v.z); a5 += bhi(v.z); a6 += blo(v.w); a7 += bhi(v.w);
    }
    a0 += __shfl_xor(a0, 16); a0 += __shfl_xor(a0, 32);
    a1 += __shfl_xor(a1, 16); a1 += __shfl_xor(a1, 32);
    a2 += __shfl_xor(a2, 16); a2 += __shfl_xor(a2, 32);
    a3 += __shfl_xor(a3, 16); a3 += __shfl_xor(a3, 32);
    a4 += __shfl_xor(a4, 16); a4 += __shfl_xor(a4, 32);
    a5 += __shfl_xor(a5, 16); a5 += __shfl_xor(a5, 32);
    a6 += __shfl_xor(a6, 16); a6 += __shfl_xor(a6, 32);
    a7 += __shfl_xor(a7, 16); a7 += __shfl_xor(a7, 32);
    if (q == 0) {
        float inv = 1.0f / fmaxf((float)(end - beg), 1.0f);
        uint4 o;
        o.x = (unsigned int)f2b(a0 * inv) | ((unsigned int)f2b(a1 * inv) << 16);
        o.y = (unsigned int)f2b(a2 * inv) | ((unsigned int)f2b(a3 * inv) << 16);
        o.z = (unsigned int)f2b(a4 * inv) | ((unsigned int)f2b(a5 * inv) << 16);
        o.w = (unsigned int)f2b(a6 * inv) | ((unsigned int)f2b(a7 * inv) << 16);
        *(uint4*)((char*)aggb + (((unsigned)wave << 8) + loff)) = o;
    }
}

// One wave per node over split t2: lanes 0-7 read uint2 from t2lo (64B rows),
// lanes 8-9 read uint2 from t2hi (16B rows, ~L2-resident). Lane l owns dims
// [4l, 4l+4) for l=0..9.
__global__ void agg2_add(const unsigned short* __restrict__ t2lo,
                         const unsigned short* __restrict__ t2hi,
                         const int* __restrict__ row_start,
                         const int* __restrict__ csr_src, const float* __restrict__ b2,
                         float* __restrict__ out, int N) {
    int wave = (blockIdx.x * blockDim.x + threadIdx.x) >> 6;
    int lane = threadIdx.x & 63;
    if (wave >= N) return;
    int q = lane >> 4;
    int l = lane & 15;
    int beg = row_start[wave], end = row_start[wave + 1];
    const char* lob = (const char*)t2lo;
    const char* hib = (const char*)t2hi;
    bool isLo = (l < 8);
    bool active = (l < 10);
    unsigned loff = isLo ? ((unsigned)l << 3) : ((unsigned)(l - 8) << 3);

    float a0 = 0.f, a1 = 0.f, a2 = 0.f, a3 = 0.f;

    int e = beg;
    for (; e + 16 <= end; e += 16) {
        int eq = e + 4 * q;
        int s0 = csr_src[eq + 0];
        int s1 = csr_src[eq + 1];
        int s2 = csr_src[eq + 2];
        int s3 = csr_src[eq + 3];
        if (active) {
            uint2 v0, v1, v2, v3;
            if (isLo) {
                v0 = *(const uint2*)(lob + (((unsigned)s0 << 6) + loff));
                v1 = *(const uint2*)(lob + (((unsigned)s1 << 6) + loff));
                v2 = *(const uint2*)(lob + (((unsigned)s2 << 6) + loff));
                v3 = *(const uint2*)(lob + (((unsigned)s3 << 6) + loff));
            } else {
                v0 = *(const uint2*)(hib + (((unsigned)s0 << 4) + loff));
                v1 = *(const uint2*)(hib + (((unsigned)s1 << 4) + loff));
                v2 = *(const uint2*)(hib + (((unsigned)s2 << 4) + loff));
                v3 = *(const uint2*)(hib + (((unsigned)s3 << 4) + loff));
            }
            a0 += blo(v0.x) + blo(v1.x) + blo(v2.x) + blo(v3.x);
            a1 += bhi(v0.x) + bhi(v1.x) + bhi(v2.x) + bhi(v3.x);
            a2 += blo(v0.y) + blo(v1.y) + blo(v2.y) + blo(v3.y);
            a3 += bhi(v0.y) + bhi(v1.y) + bhi(v2.y) + bhi(v3.y);
        }
    }
    for (; e + 4 <= end; e += 4) {
        int s = csr_src[e + q];
        if (active) {
            uint2 v = isLo ? *(const uint2*)(lob + (((unsigned)s << 6) + loff))
                           : *(const uint2*)(hib + (((unsigned)s << 4) + loff));
            a0 += blo(v.x); a1 += bhi(v.x); a2 += blo(v.y); a3 += bhi(v.y);
        }
    }
    int rem = end - e;
    if (q < rem) {
        int s = csr_src[e + q];
        if (active) {
            uint2 v = isLo ? *(const uint2*)(lob + (((unsigned)s << 6) + loff))
                           : *(const uint2*)(hib + (((unsigned)s << 4) + loff));
            a0 += blo(v.x); a1 += bhi(v.x); a2 += blo(v.y); a3 += bhi(v.y);
        }
    }
    a0 += __shfl_xor(a0, 16); a0 += __shfl_xor(a0, 32);
    a1 += __shfl_xor(a1, 16); a1 += __shfl_xor(a1, 32);
    a2 += __shfl_xor(a2, 16); a2 += __shfl_xor(a2, 32);
    a3 += __shfl_xor(a3, 16); a3 += __shfl_xor(a3, 32);
    if (q == 0 && active) {
        float inv = 1.0f / fmaxf((float)(end - beg), 1.0f);
        float4 bb = ((const float4*)b2)[l];
        float4* op = (float4*)((char*)out + ((unsigned)wave * 160u + ((unsigned)l << 4)));
        float4 cur = *op;
        cur.x += a0 * inv + bb.x;
        cur.y += a1 * inv + bb.y;
        cur.z += a2 * inv + bb.z;
        cur.w += a3 * inv + bb.w;
        *op = cur;
    }
}

// --------------------------------------------------------------- fused GEMM
// Phase 1: h1 = relu([xb|aggb] @ W1cat + b1) into LDS (128x136-stride bf16).
// Phase 2: [out_self | t2lo|t2hi] = h1_tile @ W2cat (W2t in LDS, loaded once).

__global__ __launch_bounds__(256) void gemm12_mfma(
    const unsigned short* __restrict__ xb, const unsigned short* __restrict__ aggb,
    const unsigned short* __restrict__ W1t, const unsigned short* __restrict__ W2t,
    const float* __restrict__ b1, float* __restrict__ out,
    unsigned short* __restrict__ t2lo, unsigned short* __restrict__ t2hi, int N) {

    __shared__ unsigned short As[128 * 40];
    __shared__ unsigned short Bs[128 * 40];
    __shared__ unsigned short Hs[128 * 136];   // h1 tile, +8 pad (16B-aligned rows)
    __shared__ unsigned short B2[80 * 136];    // W2t resident

    int tid = threadIdx.x;
    int wave = tid >> 6, lane = tid & 63;
    int row0 = blockIdx.x * 128;
    int m = lane & 15, quad = lane >> 4;

    // stage W2t once (80 rows x 128 k = 1280 float4s)
    for (int idx = tid; idx < 1280; idx += 256) {
        int r = idx >> 4, seg = idx & 15;
        *(float4*)&B2[r * 136 + seg * 8] = *(const float4*)(W2t + (size_t)r * 128 + seg * 8);
    }

    f32x4 acc[2][8];
#pragma unroll
    for (int i = 0; i < 2; i++)
#pragma unroll
        for (int j = 0; j < 8; j++) acc[i][j] = (f32x4){0.f, 0.f, 0.f, 0.f};

    for (int k0 = 0; k0 < 256; k0 += 32) {
        __syncthreads();
        {
            int r = tid >> 1, kk = (tid & 1) * 16;
            int row = row0 + r;
            float4 v0 = make_float4(0, 0, 0, 0), v1 = v0;
            if (row < N) {
                const unsigned short* s = (k0 < 128)
                    ? (xb + (size_t)row * 128 + k0 + kk)
                    : (aggb + (size_t)row * 128 + (k0 - 128) + kk);
                const float4* p = (const float4*)s;
                v0 = p[0]; v1 = p[1];
            }
            *(float4*)&As[r * 40 + kk] = v0;
            *(float4*)&As[r * 40 + kk + 8] = v1;
            const float4* q2 = (const float4*)(W1t + (size_t)r * 256 + k0 + kk);
            float4 w0 = q2[0], w1 = q2[1];
            *(float4*)&Bs[r * 40 + kk] = w0;
            *(float4*)&Bs[r * 40 + kk + 8] = w1;
        }
        __syncthreads();

        bf16x8 af0 = *(bf16x8*)&As[(wave * 32 + m) * 40 + quad * 8];
        bf16x8 af1 = *(bf16x8*)&As[(wave * 32 + 16 + m) * 40 + quad * 8];
#pragma unroll
        for (int j = 0; j < 8; j++) {
            bf16x8 bfg = *(bf16x8*)&Bs[(j * 16 + m) * 40 + quad * 8];
            acc[0][j] = __builtin_amdgcn_mfma_f32_16x16x32_bf16(af0, bfg, acc[0][j], 0, 0, 0);
            acc[1][j] = __builtin_amdgcn_mfma_f32_16x16x32_bf16(af1, bfg, acc[1][j], 0, 0, 0);
        }
    }

    // epilogue 1: bias+relu -> Hs (bf16).  C/D: col=lane&15, row=quad*4+reg.
#pragma unroll
    for (int j = 0; j < 8; j++) {
        int col = j * 16 + m;
        float bias = b1[col];
#pragma unroll
        for (int i = 0; i < 2; i++) {
#pragma unroll
            for (int r = 0; r < 4; r++) {
                int rl = wave * 32 + i * 16 + quad * 4 + r;
                Hs[rl * 136 + col] = f2b(fmaxf(acc[i][j][r] + bias, 0.f));
            }
        }
    }
    __syncthreads();

    // phase 2: K=128 over Hs, 80 cols from B2.
    f32x4 acc2[2][5];
#pragma unroll
    for (int i = 0; i < 2; i++)
#pragma unroll
        for (int j = 0; j < 5; j++) acc2[i][j] = (f32x4){0.f, 0.f, 0.f, 0.f};

#pragma unroll
    for (int k0 = 0; k0 < 128; k0 += 32) {
        bf16x8 af0 = *(bf16x8*)&Hs[(wave * 32 + m) * 136 + k0 + quad * 8];
        bf16x8 af1 = *(bf16x8*)&Hs[(wave * 32 + 16 + m) * 136 + k0 + quad * 8];
#pragma unroll
        for (int j = 0; j < 5; j++) {
            bf16x8 bfg = *(bf16x8*)&B2[(j * 16 + m) * 136 + k0 + quad * 8];
            acc2[0][j] = __builtin_amdgcn_mfma_f32_16x16x32_bf16(af0, bfg, acc2[0][j], 0, 0, 0);
            acc2[1][j] = __builtin_amdgcn_mfma_f32_16x16x32_bf16(af1, bfg, acc2[1][j], 0, 0, 0);
        }
    }

#pragma unroll
    for (int j = 0; j < 5; j++) {
        int col = j * 16 + m;
#pragma unroll
        for (int i = 0; i < 2; i++) {
#pragma unroll
            for (int r = 0; r < 4; r++) {
                int row = row0 + wave * 32 + i * 16 + quad * 4 + r;
                if (row < N) {
                    float v = acc2[i][j][r];
                    if (col < 40) {
                        out[(size_t)row * 40 + col] = v;
                    } else {
                        int td = col - 40;
                        if (td < 32) t2lo[(size_t)row * 32 + td] = f2b(v);
                        else         t2hi[(size_t)row * 8 + (td - 32)] = f2b(v);
                    }
                }
            }
        }
    }
}

// ------------------------------------------------------------------ launch

extern "C" void kernel_launch(void* const* d_in, const int* in_sizes, int n_in,
                              void* d_out, int out_size, void* d_ws, size_t ws_size,
                              hipStream_t stream) {
    const float* x   = (const float*)d_in[0];
    const int*   src = (const int*)d_in[1];
    const int*   dst = (const int*)d_in[2];
    const float* W1s = (const float*)d_in[3];
    const float* W1n = (const float*)d_in[4];
    const float* b1  = (const float*)d_in[5];
    const float* W2s = (const float*)d_in[6];
    const float* W2n = (const float*)d_in[7];
    const float* b2  = (const float*)d_in[8];
    float* out = (float*)d_out;

    int N = in_sizes[0] / 128;
    int E = in_sizes[1];
    int nbins = (N + BIN_SIZE - 1) / BIN_SIZE;   // 782 for N=100000
    int M = nbins * NB;

    char* ws = (char*)d_ws;
    int*            row_start  = (int*)(ws + OFF_ROWSTART);
    int*            hist       = (int*)(ws + OFF_HIST);
    int*            scanned    = (int*)(ws + OFF_SCAN);
    int*            bsums      = (int*)(ws + OFF_BSUMS);
    int*            boffs      = (int*)(ws + OFF_BOFFS);
    unsigned int*   packed     = (unsigned int*)(ws + OFF_PACKED);
    int*            csr_src    = (int*)(ws + OFF_CSR);
    unsigned short* W1t        = (unsigned short*)(ws + OFF_W1T);
    unsigned short* W2t        = (unsigned short*)(ws + OFF_W2T);
    unsigned short* xb         = (unsigned short*)(ws + OFF_XB);
    unsigned short* aggb       = (unsigned short*)(ws + OFF_AGGB);
    unsigned short* t2lo       = (unsigned short*)(ws + OFF_T2LO);
    unsigned short* t2hi       = (unsigned short*)(ws + OFF_T2HI);

    int scanBlocks = (M + 255) / 256;

    hist_local<<<NB, 256, 0, stream>>>(dst, hist, E, nbins);
    scan1<<<scanBlocks, 256, 0, stream>>>(hist, scanned, bsums, M);
    scan2<<<1, 1024, 0, stream>>>(bsums, boffs, scanBlocks);
    scan3<<<scanBlocks, 256, 0, stream>>>(scanned, boffs, M);
    scatter_det<<<NB, 256, 0, stream>>>(src, dst, scanned, packed, E, nbins);
    bin_fill<<<nbins, 256, 0, stream>>>(packed, scanned, row_start, csr_src, N, nbins, E);

    int n8 = N * 128 / 8;
    cast_bf16<<<(n8 + 255) / 256, 256, 0, stream>>>(x, xb, n8);
    prep_weights<<<208, 256, 0, stream>>>(W1s, W1n, W2s, W2n, W1t, W2t);

    int aggBlocks = (N * 64 + 255) / 256;
    agg_mean_bf16<<<aggBlocks, 256, 0, stream>>>(xb, row_start, csr_src, aggb, N);
    gemm12_mfma<<<(N + 127) / 128, 256, 0, stream>>>(xb, aggb, W1t, W2t, b1, out, t2lo, t2hi, N);
    agg2_add<<<aggBlocks, 256, 0, stream>>>(t2lo, t2hi, row_start, csr_src, b2, out, N);
}

// Round 9
// 294.945 us; speedup vs baseline: 2.3577x; 1.0406x over previous
//
#include <hip/hip_runtime.h>

// GraphSAGE 2-layer forward on MI355X.
// Round 9: fp8-e4m3 gather for layer-1 aggregation (halves row bytes AND
// unpack VALU; error enters pre-mean and is shrunk ~10x by W1n), scan3
// folded into scatter/bin_fill cursor seeding, cast+weight-prep merged.
// CSR: deterministic counting sort. GEMM: fused gemm12 (h1 tile in LDS).
// agg2: bf16 split t2lo/t2hi (fp8 there would hit the output directly).

typedef __attribute__((ext_vector_type(8))) short bf16x8;
typedef __attribute__((ext_vector_type(4))) float f32x4;
typedef __attribute__((ext_vector_type(2))) float f32x2;

#define BIN_SHIFT 7
#define BIN_SIZE  128
#define NB        256          // scatter blocks (= scan block size!)

#define OFF_ROWSTART (1ull << 20)   // 400 KB
#define OFF_HIST     (2ull << 20)   // 800 KB  hist[bin*NB + blk]
#define OFF_SCAN     (3ull << 20)   // 800 KB  block-local exclusive prefix
#define OFF_BSUMS    (4ull << 20)
#define OFF_BOFFS    ((4ull << 20) + (64ull << 10))
#define OFF_PACKED   (5ull << 20)   // 6.4 MB
#define OFF_CSR      (12ull << 20)  // 6.4 MB
#define OFF_W1T      (19ull << 20)  // 64 KB
#define OFF_W2T      (20ull << 20)  // 20 KB
#define OFF_XB       (21ull << 20)  // 25.6 MB bf16 (gemm12 self-term)
#define OFF_XQ       (47ull << 20)  // 12.8 MB fp8 (agg gather)
#define OFF_AGGB     (61ull << 20)  // 25.6 MB bf16
#define OFF_T2LO     (87ull << 20)  // 6.4 MB  (32 bf16/row)
#define OFF_T2HI     (94ull << 20)  // 1.6 MB  (8 bf16/row)

static __device__ __forceinline__ unsigned short f2b(float f) {
    unsigned int u = __float_as_uint(f);
    u += 0x7fffu + ((u >> 16) & 1u);   // round-to-nearest-even
    return (unsigned short)(u >> 16);
}
static __device__ __forceinline__ float blo(unsigned int v) { return __uint_as_float(v << 16); }
static __device__ __forceinline__ float bhi(unsigned int v) { return __uint_as_float(v & 0xffff0000u); }

// ------------------------------------------------- CSR via counting sort

__global__ __launch_bounds__(256) void hist_local(
    const int* __restrict__ dst, int* __restrict__ hist, int E, int nbins) {
    __shared__ int h[1024];
    int b = blockIdx.x, t = threadIdx.x;
    for (int i = t; i < nbins; i += 256) h[i] = 0;
    __syncthreads();
    int chunk = (E + NB - 1) / NB;
    int base = b * chunk;
    int lim = min(base + chunk, E);
    for (int e = base + t; e < lim; e += 256)
        atomicAdd(&h[dst[e] >> BIN_SHIFT], 1);
    __syncthreads();
    for (int i = t; i < nbins; i += 256)
        hist[i * NB + b] = h[i];
}

__global__ void scan1(const int* __restrict__ in, int* __restrict__ tmp,
                      int* __restrict__ bsums, int M) {
    __shared__ int s[256];
    int t = threadIdx.x;
    int i = blockIdx.x * 256 + t;
    int v = (i < M) ? in[i] : 0;
    s[t] = v;
    __syncthreads();
    for (int off = 1; off < 256; off <<= 1) {
        int u = (t >= off) ? s[t - off] : 0;
        __syncthreads();
        s[t] += u;
        __syncthreads();
    }
    if (i < M) tmp[i] = s[t] - v;
    if (t == 255) bsums[blockIdx.x] = s[t];
}

__global__ void scan2(const int* __restrict__ bsums, int* __restrict__ boffs, int nb) {
    __shared__ int s[1024];
    int t = threadIdx.x;
    int v = (t < nb) ? bsums[t] : 0;
    s[t] = v;
    __syncthreads();
    for (int off = 1; off < 1024; off <<= 1) {
        int u = (t >= off) ? s[t - off] : 0;
        __syncthreads();
        s[t] += u;
        __syncthreads();
    }
    if (t < nb) boffs[t] = s[t] - v;
}

// Global exclusive prefix at flat index i = tmp[i] + boffs[i>>8].
// For i = bin*NB + b (NB=256): block index == bin, so offset = boffs[bin].
__global__ __launch_bounds__(256) void scatter_det(
    const int* __restrict__ src, const int* __restrict__ dst,
    const int* __restrict__ tmp, const int* __restrict__ boffs,
    unsigned int* __restrict__ packed, int E, int nbins) {
    __shared__ int cur[1024];
    int b = blockIdx.x, t = threadIdx.x;
    for (int i = t; i < nbins; i += 256) cur[i] = tmp[i * NB + b] + boffs[i];
    __syncthreads();
    int chunk = (E + NB - 1) / NB;
    int base = b * chunk;
    int lim = min(base + chunk, E);
    for (int e = base + t; e < lim; e += 256) {
        int d = dst[e];
        int bin = d >> BIN_SHIFT;
        int pos = atomicAdd(&cur[bin], 1);   // LDS atomic
        packed[pos] = ((unsigned int)(d & (BIN_SIZE - 1)) << 20) | (unsigned int)src[e];
    }
}

__global__ __launch_bounds__(256) void bin_fill(
    const unsigned int* __restrict__ packed, const int* __restrict__ tmp,
    const int* __restrict__ boffs,
    int* __restrict__ row_start, int* __restrict__ csr_src, int N, int nbins, int E) {
    __shared__ int cnt[BIN_SIZE];
    __shared__ int pre[BIN_SIZE];
    __shared__ int ex[BIN_SIZE];
    int b = blockIdx.x;
    int t = threadIdx.x;
    int node0 = b << BIN_SHIFT;
    int beg = tmp[b * NB] + boffs[b];
    int end = (b + 1 < nbins) ? (tmp[(b + 1) * NB] + boffs[b + 1]) : E;

    if (t < BIN_SIZE) cnt[t] = 0;
    __syncthreads();
    for (int i = beg + t; i < end; i += 256)
        atomicAdd(&cnt[packed[i] >> 20], 1);
    __syncthreads();
    if (t < BIN_SIZE) pre[t] = cnt[t];
    __syncthreads();
    for (int off = 1; off < BIN_SIZE; off <<= 1) {
        int u = (t < BIN_SIZE && t >= off) ? pre[t - off] : 0;
        __syncthreads();
        if (t < BIN_SIZE) pre[t] += u;
        __syncthreads();
    }
    if (t < BIN_SIZE) {
        ex[t] = pre[t] - cnt[t];
        int node = node0 + t;
        if (node < N) row_start[node] = beg + ex[t];
        cnt[t] = 0;
    }
    if (b == nbins - 1 && t == 0) row_start[N] = E;
    __syncthreads();
    for (int i = beg + t; i < end; i += 256) {
        unsigned int p = packed[i];
        int dl = p >> 20;
        int s = p & 0xFFFFF;
        int ofs = atomicAdd(&cnt[dl], 1);
        csr_src[beg + ex[dl] + ofs] = s;
    }
}

// ------------------------------------------------------------- prep kernel
// blocks [0, castBlocks): x -> xb (bf16) + xq (fp8 e4m3), 16 dims/thread.
// blocks [castBlocks, +128): W1t col transpose; then 80 blocks: W2t.

__global__ void cast_prep(const float* __restrict__ x,
                          const float* __restrict__ W1s, const float* __restrict__ W1n,
                          const float* __restrict__ W2s, const float* __restrict__ W2n,
                          unsigned short* __restrict__ xb, unsigned char* __restrict__ xq,
                          unsigned short* __restrict__ W1t, unsigned short* __restrict__ W2t,
                          int n16, int castBlocks) {
    int blk = blockIdx.x, t = threadIdx.x;
    if (blk < castBlocks) {
        int i = blk * 256 + t;
        if (i >= n16) return;
        const float4* p = (const float4*)x + (size_t)i * 4;
        float4 v0 = p[0], v1 = p[1], v2 = p[2], v3 = p[3];
        float f[16] = {v0.x, v0.y, v0.z, v0.w, v1.x, v1.y, v1.z, v1.w,
                       v2.x, v2.y, v2.z, v2.w, v3.x, v3.y, v3.z, v3.w};
        unsigned short ob[16];
#pragma unroll
        for (int k = 0; k < 16; k++) ob[k] = f2b(f[k]);
        *(float4*)(xb + (size_t)i * 16) = *(float4*)&ob[0];
        *(float4*)(xb + (size_t)i * 16 + 8) = *(float4*)&ob[8];
        unsigned int w[4];
#pragma unroll
        for (int k = 0; k < 4; k++) {
            int u = __builtin_amdgcn_cvt_pk_fp8_f32(f[4 * k + 0], f[4 * k + 1], 0, false);
            u = __builtin_amdgcn_cvt_pk_fp8_f32(f[4 * k + 2], f[4 * k + 3], u, true);
            w[k] = (unsigned int)u;
        }
        *(uint4*)(xq + (size_t)i * 16) = *(uint4*)w;
    } else if (blk < castBlocks + 128) {
        int c = blk - castBlocks;
        float v = (t < 128) ? W1s[(size_t)t * 128 + c] : W1n[(size_t)(t - 128) * 128 + c];
        W1t[(size_t)c * 256 + t] = f2b(v);
    } else if (t < 128) {
        int c = blk - castBlocks - 128;
        float v = (c < 40) ? W2s[(size_t)t * 40 + c] : W2n[(size_t)t * 40 + (c - 40)];
        W2t[(size_t)c * 128 + t] = f2b(v);
    }
}

// ------------------------------------------------------- aggregation kernels

// One wave per node over fp8 x rows (128 B). Group g = lane>>3 handles edges
// e+g (and e+8+g); lane-in-group l = lane&7 owns dims [16l, 16l+16) via one
// uint4. HW cvt_pk_f32_fp8 unpack (1 inst / 2 dims). 32-bit byte offsets.
__global__ void agg_mean_fp8(const unsigned char* __restrict__ xq,
                             const int* __restrict__ row_start,
                             const int* __restrict__ csr_src,
                             unsigned short* __restrict__ aggb, int N) {
    int wave = (blockIdx.x * blockDim.x + threadIdx.x) >> 6;
    int lane = threadIdx.x & 63;
    if (wave >= N) return;
    int g = lane >> 3;
    int l = lane & 7;
    int beg = row_start[wave], end = row_start[wave + 1];
    const char* xbase = (const char*)xq;
    unsigned loff = (unsigned)l << 4;

    float a[16];
#pragma unroll
    for (int k = 0; k < 16; k++) a[k] = 0.f;

#define ACC16(V)                                                        \
    {                                                                   \
        unsigned int wd[4] = {(V).x, (V).y, (V).z, (V).w};              \
        _Pragma("unroll")                                               \
        for (int k = 0; k < 4; k++) {                                   \
            f32x2 p0 = __builtin_amdgcn_cvt_pk_f32_fp8(wd[k], false);   \
            f32x2 p1 = __builtin_amdgcn_cvt_pk_f32_fp8(wd[k], true);    \
            a[4 * k + 0] += p0.x; a[4 * k + 1] += p0.y;                 \
            a[4 * k + 2] += p1.x; a[4 * k + 3] += p1.y;                 \
        }                                                               \
    }

    int e = beg;
    for (; e + 16 <= end; e += 16) {
        int s0 = csr_src[e + g];
        int s1 = csr_src[e + 8 + g];
        uint4 v0 = *(const uint4*)(xbase + (((unsigned)s0 << 7) + loff));
        uint4 v1 = *(const uint4*)(xbase + (((unsigned)s1 << 7) + loff));
        ACC16(v0);
        ACC16(v1);
    }
    for (; e + 8 <= end; e += 8) {
        int s = csr_src[e + g];
        uint4 v = *(const uint4*)(xbase + (((unsigned)s << 7) + loff));
        ACC16(v);
    }
    int rem = end - e;
    if (g < rem) {
        int s = csr_src[e + g];
        uint4 v = *(const uint4*)(xbase + (((unsigned)s << 7) + loff));
        ACC16(v);
    }
#undef ACC16

#pragma unroll
    for (int k = 0; k < 16; k++) {
        a[k] += __shfl_xor(a[k], 8);
        a[k] += __shfl_xor(a[k], 16);
        a[k] += __shfl_xor(a[k], 32);
    }
    if (g == 0) {
        float inv = 1.0f / fmaxf((float)(end - beg), 1.0f);
        unsigned int ow[8];
#pragma unroll
        for (int k = 0; k < 8; k++)
            ow[k] = (unsigned int)f2b(a[2 * k] * inv) |
                    ((unsigned int)f2b(a[2 * k + 1] * inv) << 16);
        char* obase = (char*)aggb + (((unsigned)wave << 8) + ((unsigned)l << 5));
        *(uint4*)obase = *(uint4*)&ow[0];
        *(uint4*)(obase + 16) = *(uint4*)&ow[4];
    }
}

// One wave per node over split t2 (bf16): lanes 0-7 of each quarter read
// uint2 from t2lo (64B rows), lanes 8-9 from t2hi (16B rows, ~L2-resident).
__global__ void agg2_add(const unsigned short* __restrict__ t2lo,
                         const unsigned short* __restrict__ t2hi,
                         const int* __restrict__ row_start,
                         const int* __restrict__ csr_src, const float* __restrict__ b2,
                         float* __restrict__ out, int N) {
    int wave = (blockIdx.x * blockDim.x + threadIdx.x) >> 6;
    int lane = threadIdx.x & 63;
    if (wave >= N) return;
    int q = lane >> 4;
    int l = lane & 15;
    int beg = row_start[wave], end = row_start[wave + 1];
    const char* lob = (const char*)t2lo;
    const char* hib = (const char*)t2hi;
    bool isLo = (l < 8);
    bool active = (l < 10);
    unsigned loff = isLo ? ((unsigned)l << 3) : ((unsigned)(l - 8) << 3);

    float a0 = 0.f, a1 = 0.f, a2 = 0.f, a3 = 0.f;

    int e = beg;
    for (; e + 16 <= end; e += 16) {
        int eq = e + 4 * q;
        int s0 = csr_src[eq + 0];
        int s1 = csr_src[eq + 1];
        int s2 = csr_src[eq + 2];
        int s3 = csr_src[eq + 3];
        if (active) {
            uint2 v0, v1, v2, v3;
            if (isLo) {
                v0 = *(const uint2*)(lob + (((unsigned)s0 << 6) + loff));
                v1 = *(const uint2*)(lob + (((unsigned)s1 << 6) + loff));
                v2 = *(const uint2*)(lob + (((unsigned)s2 << 6) + loff));
                v3 = *(const uint2*)(lob + (((unsigned)s3 << 6) + loff));
            } else {
                v0 = *(const uint2*)(hib + (((unsigned)s0 << 4) + loff));
                v1 = *(const uint2*)(hib + (((unsigned)s1 << 4) + loff));
                v2 = *(const uint2*)(hib + (((unsigned)s2 << 4) + loff));
                v3 = *(const uint2*)(hib + (((unsigned)s3 << 4) + loff));
            }
            a0 += blo(v0.x) + blo(v1.x) + blo(v2.x) + blo(v3.x);
            a1 += bhi(v0.x) + bhi(v1.x) + bhi(v2.x) + bhi(v3.x);
            a2 += blo(v0.y) + blo(v1.y) + blo(v2.y) + blo(v3.y);
            a3 += bhi(v0.y) + bhi(v1.y) + bhi(v2.y) + bhi(v3.y);
        }
    }
    for (; e + 4 <= end; e += 4) {
        int s = csr_src[e + q];
        if (active) {
            uint2 v = isLo ? *(const uint2*)(lob + (((unsigned)s << 6) + loff))
                           : *(const uint2*)(hib + (((unsigned)s << 4) + loff));
            a0 += blo(v.x); a1 += bhi(v.x); a2 += blo(v.y); a3 += bhi(v.y);
        }
    }
    int rem = end - e;
    if (q < rem) {
        int s = csr_src[e + q];
        if (active) {
            uint2 v = isLo ? *(const uint2*)(lob + (((unsigned)s << 6) + loff))
                           : *(const uint2*)(hib + (((unsigned)s << 4) + loff));
            a0 += blo(v.x); a1 += bhi(v.x); a2 += blo(v.y); a3 += bhi(v.y);
        }
    }
    a0 += __shfl_xor(a0, 16); a0 += __shfl_xor(a0, 32);
    a1 += __shfl_xor(a1, 16); a1 += __shfl_xor(a1, 32);
    a2 += __shfl_xor(a2, 16); a2 += __shfl_xor(a2, 32);
    a3 += __shfl_xor(a3, 16); a3 += __shfl_xor(a3, 32);
    if (q == 0 && active) {
        float inv = 1.0f / fmaxf((float)(end - beg), 1.0f);
        float4 bb = ((const float4*)b2)[l];
        float4* op = (float4*)((char*)out + ((unsigned)wave * 160u + ((unsigned)l << 4)));
        float4 cur = *op;
        cur.x += a0 * inv + bb.x;
        cur.y += a1 * inv + bb.y;
        cur.z += a2 * inv + bb.z;
        cur.w += a3 * inv + bb.w;
        *op = cur;
    }
}

// --------------------------------------------------------------- fused GEMM
// Phase 1: h1 = relu([xb|aggb] @ W1cat + b1) into LDS (128x136-stride bf16).
// Phase 2: [out_self | t2lo|t2hi] = h1_tile @ W2cat (W2t in LDS, loaded once).

__global__ __launch_bounds__(256) void gemm12_mfma(
    const unsigned short* __restrict__ xb, const unsigned short* __restrict__ aggb,
    const unsigned short* __restrict__ W1t, const unsigned short* __restrict__ W2t,
    const float* __restrict__ b1, float* __restrict__ out,
    unsigned short* __restrict__ t2lo, unsigned short* __restrict__ t2hi, int N) {

    __shared__ unsigned short As[128 * 40];
    __shared__ unsigned short Bs[128 * 40];
    __shared__ unsigned short Hs[128 * 136];   // h1 tile, +8 pad
    __shared__ unsigned short B2[80 * 136];    // W2t resident

    int tid = threadIdx.x;
    int wave = tid >> 6, lane = tid & 63;
    int row0 = blockIdx.x * 128;
    int m = lane & 15, quad = lane >> 4;

    for (int idx = tid; idx < 1280; idx += 256) {
        int r = idx >> 4, seg = idx & 15;
        *(float4*)&B2[r * 136 + seg * 8] = *(const float4*)(W2t + (size_t)r * 128 + seg * 8);
    }

    f32x4 acc[2][8];
#pragma unroll
    for (int i = 0; i < 2; i++)
#pragma unroll
        for (int j = 0; j < 8; j++) acc[i][j] = (f32x4){0.f, 0.f, 0.f, 0.f};

    for (int k0 = 0; k0 < 256; k0 += 32) {
        __syncthreads();
        {
            int r = tid >> 1, kk = (tid & 1) * 16;
            int row = row0 + r;
            float4 v0 = make_float4(0, 0, 0, 0), v1 = v0;
            if (row < N) {
                const unsigned short* s = (k0 < 128)
                    ? (xb + (size_t)row * 128 + k0 + kk)
                    : (aggb + (size_t)row * 128 + (k0 - 128) + kk);
                const float4* p = (const float4*)s;
                v0 = p[0]; v1 = p[1];
            }
            *(float4*)&As[r * 40 + kk] = v0;
            *(float4*)&As[r * 40 + kk + 8] = v1;
            const float4* q2 = (const float4*)(W1t + (size_t)r * 256 + k0 + kk);
            float4 w0 = q2[0], w1 = q2[1];
            *(float4*)&Bs[r * 40 + kk] = w0;
            *(float4*)&Bs[r * 40 + kk + 8] = w1;
        }
        __syncthreads();

        bf16x8 af0 = *(bf16x8*)&As[(wave * 32 + m) * 40 + quad * 8];
        bf16x8 af1 = *(bf16x8*)&As[(wave * 32 + 16 + m) * 40 + quad * 8];
#pragma unroll
        for (int j = 0; j < 8; j++) {
            bf16x8 bfg = *(bf16x8*)&Bs[(j * 16 + m) * 40 + quad * 8];
            acc[0][j] = __builtin_amdgcn_mfma_f32_16x16x32_bf16(af0, bfg, acc[0][j], 0, 0, 0);
            acc[1][j] = __builtin_amdgcn_mfma_f32_16x16x32_bf16(af1, bfg, acc[1][j], 0, 0, 0);
        }
    }

#pragma unroll
    for (int j = 0; j < 8; j++) {
        int col = j * 16 + m;
        float bias = b1[col];
#pragma unroll
        for (int i = 0; i < 2; i++) {
#pragma unroll
            for (int r = 0; r < 4; r++) {
                int rl = wave * 32 + i * 16 + quad * 4 + r;
                Hs[rl * 136 + col] = f2b(fmaxf(acc[i][j][r] + bias, 0.f));
            }
        }
    }
    __syncthreads();

    f32x4 acc2[2][5];
#pragma unroll
    for (int i = 0; i < 2; i++)
#pragma unroll
        for (int j = 0; j < 5; j++) acc2[i][j] = (f32x4){0.f, 0.f, 0.f, 0.f};

#pragma unroll
    for (int k0 = 0; k0 < 128; k0 += 32) {
        bf16x8 af0 = *(bf16x8*)&Hs[(wave * 32 + m) * 136 + k0 + quad * 8];
        bf16x8 af1 = *(bf16x8*)&Hs[(wave * 32 + 16 + m) * 136 + k0 + quad * 8];
#pragma unroll
        for (int j = 0; j < 5; j++) {
            bf16x8 bfg = *(bf16x8*)&B2[(j * 16 + m) * 136 + k0 + quad * 8];
            acc2[0][j] = __builtin_amdgcn_mfma_f32_16x16x32_bf16(af0, bfg, acc2[0][j], 0, 0, 0);
            acc2[1][j] = __builtin_amdgcn_mfma_f32_16x16x32_bf16(af1, bfg, acc2[1][j], 0, 0, 0);
        }
    }

#pragma unroll
    for (int j = 0; j < 5; j++) {
        int col = j * 16 + m;
#pragma unroll
        for (int i = 0; i < 2; i++) {
#pragma unroll
            for (int r = 0; r < 4; r++) {
                int row = row0 + wave * 32 + i * 16 + quad * 4 + r;
                if (row < N) {
                    float v = acc2[i][j][r];
                    if (col < 40) {
                        out[(size_t)row * 40 + col] = v;
                    } else {
                        int td = col - 40;
                        if (td < 32) t2lo[(size_t)row * 32 + td] = f2b(v);
                        else         t2hi[(size_t)row * 8 + (td - 32)] = f2b(v);
                    }
                }
            }
        }
    }
}

// ------------------------------------------------------------------ launch

extern "C" void kernel_launch(void* const* d_in, const int* in_sizes, int n_in,
                              void* d_out, int out_size, void* d_ws, size_t ws_size,
                              hipStream_t stream) {
    const float* x   = (const float*)d_in[0];
    const int*   src = (const int*)d_in[1];
    const int*   dst = (const int*)d_in[2];
    const float* W1s = (const float*)d_in[3];
    const float* W1n = (const float*)d_in[4];
    const float* b1  = (const float*)d_in[5];
    const float* W2s = (const float*)d_in[6];
    const float* W2n = (const float*)d_in[7];
    const float* b2  = (const float*)d_in[8];
    float* out = (float*)d_out;

    int N = in_sizes[0] / 128;
    int E = in_sizes[1];
    int nbins = (N + BIN_SIZE - 1) / BIN_SIZE;   // 782 for N=100000
    int M = nbins * NB;

    char* ws = (char*)d_ws;
    int*            row_start  = (int*)(ws + OFF_ROWSTART);
    int*            hist       = (int*)(ws + OFF_HIST);
    int*            scanned    = (int*)(ws + OFF_SCAN);
    int*            bsums      = (int*)(ws + OFF_BSUMS);
    int*            boffs      = (int*)(ws + OFF_BOFFS);
    unsigned int*   packed     = (unsigned int*)(ws + OFF_PACKED);
    int*            csr_src    = (int*)(ws + OFF_CSR);
    unsigned short* W1t        = (unsigned short*)(ws + OFF_W1T);
    unsigned short* W2t        = (unsigned short*)(ws + OFF_W2T);
    unsigned short* xb         = (unsigned short*)(ws + OFF_XB);
    unsigned char*  xq         = (unsigned char*)(ws + OFF_XQ);
    unsigned short* aggb       = (unsigned short*)(ws + OFF_AGGB);
    unsigned short* t2lo       = (unsigned short*)(ws + OFF_T2LO);
    unsigned short* t2hi       = (unsigned short*)(ws + OFF_T2HI);

    int scanBlocks = (M + 255) / 256;            // == nbins

    hist_local<<<NB, 256, 0, stream>>>(dst, hist, E, nbins);
    scan1<<<scanBlocks, 256, 0, stream>>>(hist, scanned, bsums, M);
    scan2<<<1, 1024, 0, stream>>>(bsums, boffs, scanBlocks);
    scatter_det<<<NB, 256, 0, stream>>>(src, dst, scanned, boffs, packed, E, nbins);
    bin_fill<<<nbins, 256, 0, stream>>>(packed, scanned, boffs, row_start, csr_src, N, nbins, E);

    int n16 = N * 128 / 16;
    int castBlocks = (n16 + 255) / 256;
    cast_prep<<<castBlocks + 128 + 80, 256, 0, stream>>>(
        x, W1s, W1n, W2s, W2n, xb, xq, W1t, W2t, n16, castBlocks);

    int aggBlocks = (N * 64 + 255) / 256;
    agg_mean_fp8<<<aggBlocks, 256, 0, stream>>>(xq, row_start, csr_src, aggb, N);
    gemm12_mfma<<<(N + 127) / 128, 256, 0, stream>>>(xb, aggb, W1t, W2t, b1, out, t2lo, t2hi, N);
    agg2_add<<<aggBlocks, 256, 0, stream>>>(t2lo, t2hi, row_start, csr_src, b2, out, N);
}

// Round 10
// 270.766 us; speedup vs baseline: 2.5682x; 1.0893x over previous
//
#include <hip/hip_runtime.h>

// GraphSAGE 2-layer forward on MI355X.
// Round 10: gather MLP fix. r9 post-mortem: fp8 halved bytes but also halved
// in-flight gathers/lane (4->2) -> no speedup (Little's law). Now:
//   agg_mean: fp8 rows, 16 lanes/edge (uint2), 16 edges/iter, 4 gathers/lane,
//   agg2:     same structure over split bf16 t2.
//   Both: PREDICATED full-issue loop via zero row at index N -> no serial
//   remainder/tail; ceil(deg/16) uniform iterations per node.
// CSR: deterministic counting sort. GEMM: fused gemm12 (h1 tile in LDS).

typedef __attribute__((ext_vector_type(8))) short bf16x8;
typedef __attribute__((ext_vector_type(4))) float f32x4;
typedef __attribute__((ext_vector_type(2))) float f32x2;

#define BIN_SHIFT 7
#define BIN_SIZE  128
#define NB        256          // scatter blocks (= scan block size!)

#define OFF_ROWSTART (1ull << 20)   // 400 KB
#define OFF_HIST     (2ull << 20)   // 800 KB  hist[bin*NB + blk]
#define OFF_SCAN     (3ull << 20)   // 800 KB  block-local exclusive prefix
#define OFF_BSUMS    (4ull << 20)
#define OFF_BOFFS    ((4ull << 20) + (64ull << 10))
#define OFF_PACKED   (5ull << 20)   // 6.4 MB
#define OFF_CSR      (12ull << 20)  // 6.4 MB
#define OFF_W1T      (19ull << 20)  // 64 KB
#define OFF_W2T      (20ull << 20)  // 20 KB
#define OFF_XB       (21ull << 20)  // 25.6 MB bf16 (gemm12 self-term)
#define OFF_XQ       (47ull << 20)  // 12.8 MB + zero row (fp8, N+1 rows)
#define OFF_AGGB     (61ull << 20)  // 25.6 MB bf16
#define OFF_T2LO     (87ull << 20)  // 6.4 MB + zero row (32 bf16/row)
#define OFF_T2HI     (94ull << 20)  // 1.6 MB + zero row (8 bf16/row)

static __device__ __forceinline__ unsigned short f2b(float f) {
    unsigned int u = __float_as_uint(f);
    u += 0x7fffu + ((u >> 16) & 1u);   // round-to-nearest-even
    return (unsigned short)(u >> 16);
}
static __device__ __forceinline__ float blo(unsigned int v) { return __uint_as_float(v << 16); }
static __device__ __forceinline__ float bhi(unsigned int v) { return __uint_as_float(v & 0xffff0000u); }

// ------------------------------------------------- CSR via counting sort

__global__ __launch_bounds__(256) void hist_local(
    const int* __restrict__ dst, int* __restrict__ hist, int E, int nbins) {
    __shared__ int h[1024];
    int b = blockIdx.x, t = threadIdx.x;
    for (int i = t; i < nbins; i += 256) h[i] = 0;
    __syncthreads();
    int chunk = (E + NB - 1) / NB;
    int base = b * chunk;
    int lim = min(base + chunk, E);
    for (int e = base + t; e < lim; e += 256)
        atomicAdd(&h[dst[e] >> BIN_SHIFT], 1);
    __syncthreads();
    for (int i = t; i < nbins; i += 256)
        hist[i * NB + b] = h[i];
}

__global__ void scan1(const int* __restrict__ in, int* __restrict__ tmp,
                      int* __restrict__ bsums, int M) {
    __shared__ int s[256];
    int t = threadIdx.x;
    int i = blockIdx.x * 256 + t;
    int v = (i < M) ? in[i] : 0;
    s[t] = v;
    __syncthreads();
    for (int off = 1; off < 256; off <<= 1) {
        int u = (t >= off) ? s[t - off] : 0;
        __syncthreads();
        s[t] += u;
        __syncthreads();
    }
    if (i < M) tmp[i] = s[t] - v;
    if (t == 255) bsums[blockIdx.x] = s[t];
}

__global__ void scan2(const int* __restrict__ bsums, int* __restrict__ boffs, int nb) {
    __shared__ int s[1024];
    int t = threadIdx.x;
    int v = (t < nb) ? bsums[t] : 0;
    s[t] = v;
    __syncthreads();
    for (int off = 1; off < 1024; off <<= 1) {
        int u = (t >= off) ? s[t - off] : 0;
        __syncthreads();
        s[t] += u;
        __syncthreads();
    }
    if (t < nb) boffs[t] = s[t] - v;
}

__global__ __launch_bounds__(256) void scatter_det(
    const int* __restrict__ src, const int* __restrict__ dst,
    const int* __restrict__ tmp, const int* __restrict__ boffs,
    unsigned int* __restrict__ packed, int E, int nbins) {
    __shared__ int cur[1024];
    int b = blockIdx.x, t = threadIdx.x;
    for (int i = t; i < nbins; i += 256) cur[i] = tmp[i * NB + b] + boffs[i];
    __syncthreads();
    int chunk = (E + NB - 1) / NB;
    int base = b * chunk;
    int lim = min(base + chunk, E);
    for (int e = base + t; e < lim; e += 256) {
        int d = dst[e];
        int bin = d >> BIN_SHIFT;
        int pos = atomicAdd(&cur[bin], 1);   // LDS atomic
        packed[pos] = ((unsigned int)(d & (BIN_SIZE - 1)) << 20) | (unsigned int)src[e];
    }
}

__global__ __launch_bounds__(256) void bin_fill(
    const unsigned int* __restrict__ packed, const int* __restrict__ tmp,
    const int* __restrict__ boffs,
    int* __restrict__ row_start, int* __restrict__ csr_src, int N, int nbins, int E) {
    __shared__ int cnt[BIN_SIZE];
    __shared__ int pre[BIN_SIZE];
    __shared__ int ex[BIN_SIZE];
    int b = blockIdx.x;
    int t = threadIdx.x;
    int node0 = b << BIN_SHIFT;
    int beg = tmp[b * NB] + boffs[b];
    int end = (b + 1 < nbins) ? (tmp[(b + 1) * NB] + boffs[b + 1]) : E;

    if (t < BIN_SIZE) cnt[t] = 0;
    __syncthreads();
    for (int i = beg + t; i < end; i += 256)
        atomicAdd(&cnt[packed[i] >> 20], 1);
    __syncthreads();
    if (t < BIN_SIZE) pre[t] = cnt[t];
    __syncthreads();
    for (int off = 1; off < BIN_SIZE; off <<= 1) {
        int u = (t < BIN_SIZE && t >= off) ? pre[t - off] : 0;
        __syncthreads();
        if (t < BIN_SIZE) pre[t] += u;
        __syncthreads();
    }
    if (t < BIN_SIZE) {
        ex[t] = pre[t] - cnt[t];
        int node = node0 + t;
        if (node < N) row_start[node] = beg + ex[t];
        cnt[t] = 0;
    }
    if (b == nbins - 1 && t == 0) row_start[N] = E;
    __syncthreads();
    for (int i = beg + t; i < end; i += 256) {
        unsigned int p = packed[i];
        int dl = p >> 20;
        int s = p & 0xFFFFF;
        int ofs = atomicAdd(&cnt[dl], 1);
        csr_src[beg + ex[dl] + ofs] = s;
    }
}

// ------------------------------------------------------------- prep kernel
// blocks [0, castBlocks): x -> xb (bf16) + xq (fp8 e4m3), 16 dims/thread.
// next 128: W1t transpose; next 80: W2t; last 1: zero rows (xq/t2lo/t2hi @ N).

__global__ void cast_prep(const float* __restrict__ x,
                          const float* __restrict__ W1s, const float* __restrict__ W1n,
                          const float* __restrict__ W2s, const float* __restrict__ W2n,
                          unsigned short* __restrict__ xb, unsigned char* __restrict__ xq,
                          unsigned short* __restrict__ W1t, unsigned short* __restrict__ W2t,
                          unsigned short* __restrict__ t2lo, unsigned short* __restrict__ t2hi,
                          int n16, int castBlocks, int N) {
    int blk = blockIdx.x, t = threadIdx.x;
    if (blk < castBlocks) {
        int i = blk * 256 + t;
        if (i >= n16) return;
        const float4* p = (const float4*)x + (size_t)i * 4;
        float4 v0 = p[0], v1 = p[1], v2 = p[2], v3 = p[3];
        float f[16] = {v0.x, v0.y, v0.z, v0.w, v1.x, v1.y, v1.z, v1.w,
                       v2.x, v2.y, v2.z, v2.w, v3.x, v3.y, v3.z, v3.w};
        unsigned short ob[16];
#pragma unroll
        for (int k = 0; k < 16; k++) ob[k] = f2b(f[k]);
        *(float4*)(xb + (size_t)i * 16) = *(float4*)&ob[0];
        *(float4*)(xb + (size_t)i * 16 + 8) = *(float4*)&ob[8];
        unsigned int w[4];
#pragma unroll
        for (int k = 0; k < 4; k++) {
            int u = __builtin_amdgcn_cvt_pk_fp8_f32(f[4 * k + 0], f[4 * k + 1], 0, false);
            u = __builtin_amdgcn_cvt_pk_fp8_f32(f[4 * k + 2], f[4 * k + 3], u, true);
            w[k] = (unsigned int)u;
        }
        *(uint4*)(xq + (size_t)i * 16) = *(uint4*)w;
    } else if (blk < castBlocks + 128) {
        int c = blk - castBlocks;
        float v = (t < 128) ? W1s[(size_t)t * 128 + c] : W1n[(size_t)(t - 128) * 128 + c];
        W1t[(size_t)c * 256 + t] = f2b(v);
    } else if (blk < castBlocks + 208) {
        if (t < 128) {
            int c = blk - castBlocks - 128;
            float v = (c < 40) ? W2s[(size_t)t * 40 + c] : W2n[(size_t)t * 40 + (c - 40)];
            W2t[(size_t)c * 128 + t] = f2b(v);
        }
    } else {
        // zero rows at index N
        if (t < 32) ((unsigned int*)(xq + (size_t)N * 128))[t] = 0u;
        else if (t < 48) ((unsigned int*)(t2lo + (size_t)N * 32))[t - 32] = 0u;
        else if (t < 52) ((unsigned int*)(t2hi + (size_t)N * 8))[t - 48] = 0u;
    }
}

// ------------------------------------------------------- aggregation kernels

// One wave per node over fp8 rows (128 B). Quarter q handles edges e+4q+k
// (k=0..3); lane-in-quarter l owns dims [8l, 8l+8) via uint2. Out-of-range
// slots clamp to zero row N -> every iteration issues 4 gathers/lane.
__global__ void agg_mean_fp8(const unsigned char* __restrict__ xq,
                             const int* __restrict__ row_start,
                             const int* __restrict__ csr_src,
                             unsigned short* __restrict__ aggb, int N) {
    int wave = (blockIdx.x * blockDim.x + threadIdx.x) >> 6;
    int lane = threadIdx.x & 63;
    if (wave >= N) return;
    int q = lane >> 4;
    int l = lane & 15;
    int beg = row_start[wave], end = row_start[wave + 1];
    const char* xbase = (const char*)xq;
    unsigned loff = (unsigned)l << 3;

    float a[8];
#pragma unroll
    for (int k = 0; k < 8; k++) a[k] = 0.f;

    for (int e = beg; e < end; e += 16) {
        int eq = e + 4 * q;
        int s[4];
#pragma unroll
        for (int k = 0; k < 4; k++) {
            int ee = eq + k;
            int idx = csr_src[min(ee, end - 1)];
            s[k] = (ee < end) ? idx : N;          // N = zero row
        }
#pragma unroll
        for (int k = 0; k < 4; k++) {
            uint2 v = *(const uint2*)(xbase + (((unsigned)s[k] << 7) + loff));
            f32x2 p0 = __builtin_amdgcn_cvt_pk_f32_fp8(v.x, false);
            f32x2 p1 = __builtin_amdgcn_cvt_pk_f32_fp8(v.x, true);
            f32x2 p2 = __builtin_amdgcn_cvt_pk_f32_fp8(v.y, false);
            f32x2 p3 = __builtin_amdgcn_cvt_pk_f32_fp8(v.y, true);
            a[0] += p0.x; a[1] += p0.y; a[2] += p1.x; a[3] += p1.y;
            a[4] += p2.x; a[5] += p2.y; a[6] += p3.x; a[7] += p3.y;
        }
    }

#pragma unroll
    for (int k = 0; k < 8; k++) {
        a[k] += __shfl_xor(a[k], 16);
        a[k] += __shfl_xor(a[k], 32);
    }
    if (q == 0) {
        float inv = 1.0f / fmaxf((float)(end - beg), 1.0f);
        unsigned int ow[4];
#pragma unroll
        for (int k = 0; k < 4; k++)
            ow[k] = (unsigned int)f2b(a[2 * k] * inv) |
                    ((unsigned int)f2b(a[2 * k + 1] * inv) << 16);
        *(uint4*)((char*)aggb + (((unsigned)wave << 8) + ((unsigned)l << 4))) = *(uint4*)ow;
    }
}

// One wave per node over split bf16 t2. Quarter q: edges e+4q+k; lanes 0-7
// read uint2 from t2lo (64B rows), lanes 8-9 from t2hi (16B rows). Zero rows
// at N make the loop fully predicated (4 gathers/lane every iteration).
__global__ void agg2_add(const unsigned short* __restrict__ t2lo,
                         const unsigned short* __restrict__ t2hi,
                         const int* __restrict__ row_start,
                         const int* __restrict__ csr_src, const float* __restrict__ b2,
                         float* __restrict__ out, int N) {
    int wave = (blockIdx.x * blockDim.x + threadIdx.x) >> 6;
    int lane = threadIdx.x & 63;
    if (wave >= N) return;
    int q = lane >> 4;
    int l = lane & 15;
    int beg = row_start[wave], end = row_start[wave + 1];
    const char* lob = (const char*)t2lo;
    const char* hib = (const char*)t2hi;
    bool isLo = (l < 8);
    bool active = (l < 10);
    unsigned loff = isLo ? ((unsigned)l << 3) : ((unsigned)(l - 8) << 3);

    float a0 = 0.f, a1 = 0.f, a2 = 0.f, a3 = 0.f;

    for (int e = beg; e < end; e += 16) {
        int eq = e + 4 * q;
        int s[4];
#pragma unroll
        for (int k = 0; k < 4; k++) {
            int ee = eq + k;
            int idx = csr_src[min(ee, end - 1)];
            s[k] = (ee < end) ? idx : N;          // N = zero row
        }
        if (active) {
#pragma unroll
            for (int k = 0; k < 4; k++) {
                uint2 v = isLo ? *(const uint2*)(lob + (((unsigned)s[k] << 6) + loff))
                               : *(const uint2*)(hib + (((unsigned)s[k] << 4) + loff));
                a0 += blo(v.x); a1 += bhi(v.x);
                a2 += blo(v.y); a3 += bhi(v.y);
            }
        }
    }

    a0 += __shfl_xor(a0, 16); a0 += __shfl_xor(a0, 32);
    a1 += __shfl_xor(a1, 16); a1 += __shfl_xor(a1, 32);
    a2 += __shfl_xor(a2, 16); a2 += __shfl_xor(a2, 32);
    a3 += __shfl_xor(a3, 16); a3 += __shfl_xor(a3, 32);
    if (q == 0 && active) {
        float inv = 1.0f / fmaxf((float)(end - beg), 1.0f);
        float4 bb = ((const float4*)b2)[l];
        float4* op = (float4*)((char*)out + ((unsigned)wave * 160u + ((unsigned)l << 4)));
        float4 cur = *op;
        cur.x += a0 * inv + bb.x;
        cur.y += a1 * inv + bb.y;
        cur.z += a2 * inv + bb.z;
        cur.w += a3 * inv + bb.w;
        *op = cur;
    }
}

// --------------------------------------------------------------- fused GEMM
// Phase 1: h1 = relu([xb|aggb] @ W1cat + b1) into LDS (128x136-stride bf16).
// Phase 2: [out_self | t2lo|t2hi] = h1_tile @ W2cat (W2t in LDS, loaded once).

__global__ __launch_bounds__(256) void gemm12_mfma(
    const unsigned short* __restrict__ xb, const unsigned short* __restrict__ aggb,
    const unsigned short* __restrict__ W1t, const unsigned short* __restrict__ W2t,
    const float* __restrict__ b1, float* __restrict__ out,
    unsigned short* __restrict__ t2lo, unsigned short* __restrict__ t2hi, int N) {

    __shared__ unsigned short As[128 * 40];
    __shared__ unsigned short Bs[128 * 40];
    __shared__ unsigned short Hs[128 * 136];   // h1 tile, +8 pad
    __shared__ unsigned short B2[80 * 136];    // W2t resident

    int tid = threadIdx.x;
    int wave = tid >> 6, lane = tid & 63;
    int row0 = blockIdx.x * 128;
    int m = lane & 15, quad = lane >> 4;

    for (int idx = tid; idx < 1280; idx += 256) {
        int r = idx >> 4, seg = idx & 15;
        *(float4*)&B2[r * 136 + seg * 8] = *(const float4*)(W2t + (size_t)r * 128 + seg * 8);
    }

    f32x4 acc[2][8];
#pragma unroll
    for (int i = 0; i < 2; i++)
#pragma unroll
        for (int j = 0; j < 8; j++) acc[i][j] = (f32x4){0.f, 0.f, 0.f, 0.f};

    for (int k0 = 0; k0 < 256; k0 += 32) {
        __syncthreads();
        {
            int r = tid >> 1, kk = (tid & 1) * 16;
            int row = row0 + r;
            float4 v0 = make_float4(0, 0, 0, 0), v1 = v0;
            if (row < N) {
                const unsigned short* s = (k0 < 128)
                    ? (xb + (size_t)row * 128 + k0 + kk)
                    : (aggb + (size_t)row * 128 + (k0 - 128) + kk);
                const float4* p = (const float4*)s;
                v0 = p[0]; v1 = p[1];
            }
            *(float4*)&As[r * 40 + kk] = v0;
            *(float4*)&As[r * 40 + kk + 8] = v1;
            const float4* q2 = (const float4*)(W1t + (size_t)r * 256 + k0 + kk);
            float4 w0 = q2[0], w1 = q2[1];
            *(float4*)&Bs[r * 40 + kk] = w0;
            *(float4*)&Bs[r * 40 + kk + 8] = w1;
        }
        __syncthreads();

        bf16x8 af0 = *(bf16x8*)&As[(wave * 32 + m) * 40 + quad * 8];
        bf16x8 af1 = *(bf16x8*)&As[(wave * 32 + 16 + m) * 40 + quad * 8];
#pragma unroll
        for (int j = 0; j < 8; j++) {
            bf16x8 bfg = *(bf16x8*)&Bs[(j * 16 + m) * 40 + quad * 8];
            acc[0][j] = __builtin_amdgcn_mfma_f32_16x16x32_bf16(af0, bfg, acc[0][j], 0, 0, 0);
            acc[1][j] = __builtin_amdgcn_mfma_f32_16x16x32_bf16(af1, bfg, acc[1][j], 0, 0, 0);
        }
    }

#pragma unroll
    for (int j = 0; j < 8; j++) {
        int col = j * 16 + m;
        float bias = b1[col];
#pragma unroll
        for (int i = 0; i < 2; i++) {
#pragma unroll
            for (int r = 0; r < 4; r++) {
                int rl = wave * 32 + i * 16 + quad * 4 + r;
                Hs[rl * 136 + col] = f2b(fmaxf(acc[i][j][r] + bias, 0.f));
            }
        }
    }
    __syncthreads();

    f32x4 acc2[2][5];
#pragma unroll
    for (int i = 0; i < 2; i++)
#pragma unroll
        for (int j = 0; j < 5; j++) acc2[i][j] = (f32x4){0.f, 0.f, 0.f, 0.f};

#pragma unroll
    for (int k0 = 0; k0 < 128; k0 += 32) {
        bf16x8 af0 = *(bf16x8*)&Hs[(wave * 32 + m) * 136 + k0 + quad * 8];
        bf16x8 af1 = *(bf16x8*)&Hs[(wave * 32 + 16 + m) * 136 + k0 + quad * 8];
#pragma unroll
        for (int j = 0; j < 5; j++) {
            bf16x8 bfg = *(bf16x8*)&B2[(j * 16 + m) * 136 + k0 + quad * 8];
            acc2[0][j] = __builtin_amdgcn_mfma_f32_16x16x32_bf16(af0, bfg, acc2[0][j], 0, 0, 0);
            acc2[1][j] = __builtin_amdgcn_mfma_f32_16x16x32_bf16(af1, bfg, acc2[1][j], 0, 0, 0);
        }
    }

#pragma unroll
    for (int j = 0; j < 5; j++) {
        int col = j * 16 + m;
#pragma unroll
        for (int i = 0; i < 2; i++) {
#pragma unroll
            for (int r = 0; r < 4; r++) {
                int row = row0 + wave * 32 + i * 16 + quad * 4 + r;
                if (row < N) {
                    float v = acc2[i][j][r];
                    if (col < 40) {
                        out[(size_t)row * 40 + col] = v;
                    } else {
                        int td = col - 40;
                        if (td < 32) t2lo[(size_t)row * 32 + td] = f2b(v);
                        else         t2hi[(size_t)row * 8 + (td - 32)] = f2b(v);
                    }
                }
            }
        }
    }
}

// ------------------------------------------------------------------ launch

extern "C" void kernel_launch(void* const* d_in, const int* in_sizes, int n_in,
                              void* d_out, int out_size, void* d_ws, size_t ws_size,
                              hipStream_t stream) {
    const float* x   = (const float*)d_in[0];
    const int*   src = (const int*)d_in[1];
    const int*   dst = (const int*)d_in[2];
    const float* W1s = (const float*)d_in[3];
    const float* W1n = (const float*)d_in[4];
    const float* b1  = (const float*)d_in[5];
    const float* W2s = (const float*)d_in[6];
    const float* W2n = (const float*)d_in[7];
    const float* b2  = (const float*)d_in[8];
    float* out = (float*)d_out;

    int N = in_sizes[0] / 128;
    int E = in_sizes[1];
    int nbins = (N + BIN_SIZE - 1) / BIN_SIZE;   // 782 for N=100000
    int M = nbins * NB;

    char* ws = (char*)d_ws;
    int*            row_start  = (int*)(ws + OFF_ROWSTART);
    int*            hist       = (int*)(ws + OFF_HIST);
    int*            scanned    = (int*)(ws + OFF_SCAN);
    int*            bsums      = (int*)(ws + OFF_BSUMS);
    int*            boffs      = (int*)(ws + OFF_BOFFS);
    unsigned int*   packed     = (unsigned int*)(ws + OFF_PACKED);
    int*            csr_src    = (int*)(ws + OFF_CSR);
    unsigned short* W1t        = (unsigned short*)(ws + OFF_W1T);
    unsigned short* W2t        = (unsigned short*)(ws + OFF_W2T);
    unsigned short* xb         = (unsigned short*)(ws + OFF_XB);
    unsigned char*  xq         = (unsigned char*)(ws + OFF_XQ);
    unsigned short* aggb       = (unsigned short*)(ws + OFF_AGGB);
    unsigned short* t2lo       = (unsigned short*)(ws + OFF_T2LO);
    unsigned short* t2hi       = (unsigned short*)(ws + OFF_T2HI);

    int scanBlocks = (M + 255) / 256;            // == nbins

    hist_local<<<NB, 256, 0, stream>>>(dst, hist, E, nbins);
    scan1<<<scanBlocks, 256, 0, stream>>>(hist, scanned, bsums, M);
    scan2<<<1, 1024, 0, stream>>>(bsums, boffs, scanBlocks);
    scatter_det<<<NB, 256, 0, stream>>>(src, dst, scanned, boffs, packed, E, nbins);
    bin_fill<<<nbins, 256, 0, stream>>>(packed, scanned, boffs, row_start, csr_src, N, nbins, E);

    int n16 = N * 128 / 16;
    int castBlocks = (n16 + 255) / 256;
    cast_prep<<<castBlocks + 128 + 80 + 1, 256, 0, stream>>>(
        x, W1s, W1n, W2s, W2n, xb, xq, W1t, W2t, t2lo, t2hi, n16, castBlocks, N);

    int aggBlocks = (N * 64 + 255) / 256;
    agg_mean_fp8<<<aggBlocks, 256, 0, stream>>>(xq, row_start, csr_src, aggb, N);
    gemm12_mfma<<<(N + 127) / 128, 256, 0, stream>>>(xb, aggb, W1t, W2t, b1, out, t2lo, t2hi, N);
    agg2_add<<<aggBlocks, 256, 0, stream>>>(t2lo, t2hi, row_start, csr_src, b2, out, N);
}